// Round 3
// baseline (677.010 us; speedup 1.0000x reference)
//
#include <hip/hip_runtime.h>
#include <math.h>

// ---------------- problem constants ----------------
#define ED    1024
#define GH    1024
#define NLAY  3
#define NHEAD 8
#define HD    128
#define NNODE 2048
#define BQ    1024
#define CAP   192

typedef unsigned short u16;
typedef __attribute__((ext_vector_type(8))) short short8;
typedef __attribute__((ext_vector_type(4))) float f32x4;

// ---------------- workspace layout (float units) ----------------
static const size_t OFF_S0  = 0;
static const size_t OFF_S1  = 2097152;
static const size_t OFF_S2  = 4194304;
static const size_t OFF_S3  = 6291456;
static const size_t OFF_S4  = 6815744;
static const size_t OFF_SV1 = 7864320;
static const size_t OFF_SV2 = 7880704;
static const size_t OFF_ACC = 7897088;
static const size_t OFF_NCNT= 7897096;   // int*
static const size_t OFF_NBR = 7899144;   // int*

// ---------------- helpers ----------------
__device__ __forceinline__ u16 f2bf(float f) {
  unsigned int u = __float_as_uint(f);
  unsigned int r = (u + 0x7fffu + ((u >> 16) & 1u)) >> 16;
  return (u16)r;
}

__device__ __forceinline__ float waveSum(float v) {
#pragma unroll
  for (int off = 32; off; off >>= 1) v += __shfl_xor(v, off, 64);
  return v;
}
__device__ __forceinline__ float waveMax(float v) {
#pragma unroll
  for (int off = 32; off; off >>= 1) v = fmaxf(v, __shfl_xor(v, off, 64));
  return v;
}
__device__ __forceinline__ float blockSum(float v) {
  __shared__ float buf[4];
  int lane = threadIdx.x & 63, wid = threadIdx.x >> 6, nw = (blockDim.x + 63) >> 6;
  v = waveSum(v);
  __syncthreads();
  if (lane == 0) buf[wid] = v;
  __syncthreads();
  float r = buf[0];
  for (int i = 1; i < nw; ++i) r += buf[i];
  return r;
}
__device__ __forceinline__ float blockMax(float v) {
  __shared__ float buf[4];
  int lane = threadIdx.x & 63, wid = threadIdx.x >> 6, nw = (blockDim.x + 63) >> 6;
  v = waveMax(v);
  __syncthreads();
  if (lane == 0) buf[wid] = v;
  __syncthreads();
  float r = buf[0];
  for (int i = 1; i < nw; ++i) r = fmaxf(r, buf[i]);
  return r;
}

// ---------------- pipelined bf16 MFMA GEMM: C = scale*(A @ Bt^T) + bias -----
// A [M,K] bf16 rm, Bt [N,K] bf16 rm, C [M,N] fp32. Tile 64 x TN, BK=32.
// M%64==0, N%TN==0, K%64==0 (nk even). 256 threads = 4 waves, wave owns 32 x TN/2.
// Register-prefetch pipeline: global->VGPR for tile k+1 issued before tile k's
// MFMAs; ds_write at next iter top. XOR-swizzled LDS (verified conflict-free).
template<int TN>
__global__ __launch_bounds__(256) void gemm_bt2(
    const u16* __restrict__ A, const u16* __restrict__ Bt,
    float* __restrict__ C, const float* __restrict__ bias,
    int M, int N, int K, float scale) {
  constexpr int NB = TN / 64;       // B 16B-segs per thread
  constexpr int WN = TN / 2;        // wave n-extent
  constexpr int MI = 2, NJ = WN / 16;
  __shared__ u16 As[64][32];
  __shared__ u16 Bs[TN][32];
  const int tid = threadIdx.x;
  const int wave = tid >> 6, lane = tid & 63;
  const int bm = blockIdx.y * 64, bn = blockIdx.x * TN;

  // staging: thread t -> row t>>2, 16B seg t&3 (coalesced global reads)
  const int sr = tid >> 2, ss = tid & 3;
  const u16* ga = A + (size_t)(bm + sr) * K + ss * 8;
  u16* wa = &As[sr][(ss ^ ((sr >> 1) & 3)) << 3];
  const u16* gb[NB];
  u16* wb[NB];
#pragma unroll
  for (int i = 0; i < NB; ++i) {
    int br = sr + i * 64;
    gb[i] = Bt + (size_t)(bn + br) * K + ss * 8;
    wb[i] = &Bs[br][(ss ^ ((br >> 1) & 3)) << 3];
  }

  // fragment read addresses (constant across K)
  const int r16 = lane & 15, kg = lane >> 4;
  const int wm = (wave >> 1) * 32, wn = (wave & 1) * WN;
  const u16* fa[MI];
  const u16* fb[NJ];
#pragma unroll
  for (int i = 0; i < MI; ++i) {
    int row = wm + i * 16 + r16;
    fa[i] = &As[row][(kg ^ ((row >> 1) & 3)) << 3];
  }
#pragma unroll
  for (int j = 0; j < NJ; ++j) {
    int col = wn + j * 16 + r16;
    fb[j] = &Bs[col][(kg ^ ((col >> 1) & 3)) << 3];
  }

  f32x4 acc[MI][NJ] = {};
  const int nk = K >> 5;            // even for all our K

  float4 p0a, p1a, p0b[NB], p1b[NB];
  p0a = *(const float4*)ga; ga += 32;
#pragma unroll
  for (int i = 0; i < NB; ++i) { p0b[i] = *(const float4*)gb[i]; gb[i] += 32; }

  for (int kt = 0; kt < nk; kt += 2) {
    // ---- even sub-iter: consume p0, prefetch p1 (tile kt+1, always valid)
    *(float4*)wa = p0a;
#pragma unroll
    for (int i = 0; i < NB; ++i) *(float4*)wb[i] = p0b[i];
    p1a = *(const float4*)ga; ga += 32;
#pragma unroll
    for (int i = 0; i < NB; ++i) { p1b[i] = *(const float4*)gb[i]; gb[i] += 32; }
    __syncthreads();
    {
      short8 av[MI], bv[NJ];
#pragma unroll
      for (int i = 0; i < MI; ++i) av[i] = *(const short8*)fa[i];
#pragma unroll
      for (int j = 0; j < NJ; ++j) bv[j] = *(const short8*)fb[j];
#pragma unroll
      for (int i = 0; i < MI; ++i)
#pragma unroll
        for (int j = 0; j < NJ; ++j)
          acc[i][j] = __builtin_amdgcn_mfma_f32_16x16x32_bf16(av[i], bv[j], acc[i][j], 0, 0, 0);
    }
    __syncthreads();
    // ---- odd sub-iter: consume p1, prefetch p0 (tile kt+2, guarded)
    *(float4*)wa = p1a;
#pragma unroll
    for (int i = 0; i < NB; ++i) *(float4*)wb[i] = p1b[i];
    if (kt + 2 < nk) {
      p0a = *(const float4*)ga; ga += 32;
#pragma unroll
      for (int i = 0; i < NB; ++i) { p0b[i] = *(const float4*)gb[i]; gb[i] += 32; }
    }
    __syncthreads();
    {
      short8 av[MI], bv[NJ];
#pragma unroll
      for (int i = 0; i < MI; ++i) av[i] = *(const short8*)fa[i];
#pragma unroll
      for (int j = 0; j < NJ; ++j) bv[j] = *(const short8*)fb[j];
#pragma unroll
      for (int i = 0; i < MI; ++i)
#pragma unroll
        for (int j = 0; j < NJ; ++j)
          acc[i][j] = __builtin_amdgcn_mfma_f32_16x16x32_bf16(av[i], bv[j], acc[i][j], 0, 0, 0);
    }
    __syncthreads();
  }

  // epilogue: C/D layout col=lane&15, row=(lane>>4)*4+reg
#pragma unroll
  for (int j = 0; j < NJ; ++j) {
    int col = bn + wn + j * 16 + r16;
    float bvv = bias ? bias[col] : 0.f;
#pragma unroll
    for (int i = 0; i < MI; ++i) {
      int row0 = bm + wm + i * 16 + kg * 4;
      float* cp = C + (size_t)row0 * N + col;
#pragma unroll
      for (int r = 0; r < 4; ++r)
        cp[(size_t)r * N] = acc[i][j][r] * scale + bvv;
    }
  }
}

// ---------------- conversion kernels ----------------
__global__ __launch_bounds__(256) void cvt_rows(const float* __restrict__ in,
                                                u16* __restrict__ out, int n4) {
  int i = blockIdx.x * 256 + threadIdx.x;
  if (i < n4) {
    float4 v = ((const float4*)in)[i];
    ushort4 o;
    o.x = f2bf(v.x); o.y = f2bf(v.y); o.z = f2bf(v.z); o.w = f2bf(v.w);
    ((ushort4*)out)[i] = o;
  }
}

// in fp32 [R][C] (batch stride inb) -> out bf16 [C][R] (batch stride outb)
__global__ __launch_bounds__(256) void cvt_transpose(
    const float* __restrict__ in, u16* __restrict__ out,
    int R, int C, long inb, long outb) {
  __shared__ float T[64][65];
  const float* ip = in + (size_t)blockIdx.z * inb;
  u16* op = out + (size_t)blockIdx.z * outb;
  int r0 = blockIdx.y * 64, c0 = blockIdx.x * 64;
  int t = threadIdx.x;
#pragma unroll
  for (int p = 0; p < 4; ++p) {
    int row = p * 16 + (t >> 4), col = (t & 15) * 4;
    float4 v = *(const float4*)&ip[(size_t)(r0 + row) * C + c0 + col];
    T[row][col] = v.x; T[row][col + 1] = v.y;
    T[row][col + 2] = v.z; T[row][col + 3] = v.w;
  }
  __syncthreads();
#pragma unroll
  for (int p = 0; p < 4; ++p) {
    int c = p * 16 + (t >> 4), r = (t & 15) * 4;
    ushort4 o;
    o.x = f2bf(T[r][c]); o.y = f2bf(T[r + 1][c]);
    o.z = f2bf(T[r + 2][c]); o.w = f2bf(T[r + 3][c]);
    *(ushort4*)&op[(size_t)(c0 + c) * R + r0 + r] = o;
  }
}

// ---------------- GNN helpers ----------------
__global__ void build_nbr(const float* __restrict__ adj, int* __restrict__ nbr,
                          int* __restrict__ ncnt) {
  __shared__ int cnt;
  int n = blockIdx.x, tid = threadIdx.x;
  if (tid == 0) cnt = 0;
  __syncthreads();
  for (int c = tid; c < NNODE; c += 256) {
    if (adj[((size_t)n << 11) + c] > 0.f) {
      int p = atomicAdd(&cnt, 1);
      if (p < CAP) nbr[n * CAP + p] = c;
    }
  }
  __syncthreads();
  if (tid == 0) ncnt[n] = cnt < CAP ? cnt : CAP;
}

__global__ __launch_bounds__(128) void s1s2_kernel(
    const float* __restrict__ WH, const float* __restrict__ a1l,
    const float* __restrict__ a2l, float* __restrict__ S1, float* __restrict__ S2) {
  __shared__ float b1[2], b2[2];
  int h = blockIdx.x & 7, n = blockIdx.x >> 3;
  int o = threadIdx.x;
  float w = WH[((size_t)n << 10) + (h << 7) + o];
  float p1 = w * a1l[(h << 7) + o];
  float p2 = w * a2l[(h << 7) + o];
  p1 = waveSum(p1); p2 = waveSum(p2);
  int lane = o & 63, wid = o >> 6;
  if (lane == 0) { b1[wid] = p1; b2[wid] = p2; }
  __syncthreads();
  if (o == 0) {
    S1[(h << 11) + n] = b1[0] + b1[1];
    S2[(h << 11) + n] = b2[0] + b2[1];
  }
}

__global__ __launch_bounds__(128) void att_pv(
    const float* __restrict__ WH, const float* __restrict__ S1,
    const float* __restrict__ S2, const int* __restrict__ nbr,
    const int* __restrict__ ncnt, float* __restrict__ HATT) {
  __shared__ float ew[CAP];
  __shared__ int   mi[CAP];
  int h = blockIdx.x & 7, n = blockIdx.x >> 3;
  int tid = threadIdx.x;
  int cnt = ncnt[n];
  float s1v = S1[(h << 11) + n];
  for (int j = tid; j < cnt; j += 128) {
    int m = nbr[n * CAP + j];
    mi[j] = m;
    float e = s1v + S2[(h << 11) + m];
    ew[j] = e > 0.f ? e : 0.2f * e;
  }
  __syncthreads();
  float lmax = -1e30f;
  for (int j = tid; j < cnt; j += 128) lmax = fmaxf(lmax, ew[j]);
  float emax = blockMax(lmax);
  float lsum = 0.f;
  for (int j = tid; j < cnt; j += 128) {
    float w = expf(ew[j] - emax);
    ew[j] = w;
    lsum += w;
  }
  float denom = blockSum(lsum);
  float inv = 1.f / denom;
  int o = tid;
  float acc = 0.f;
  for (int j = 0; j < cnt; ++j)
    acc += ew[j] * WH[((size_t)mi[j] << 10) + (h << 7) + o];
  HATT[((size_t)n << 10) + (h << 7) + o] = acc * inv;
}

// X += elu(layernorm(H)); also writes bf16 shadow Xb
__global__ __launch_bounds__(256) void ln_elu_res(
    const float* __restrict__ H, float* __restrict__ X, u16* __restrict__ Xb,
    const float* __restrict__ g, const float* __restrict__ b) {
  int row = blockIdx.x, tid = threadIdx.x;
  float4 v = *(const float4*)&H[((size_t)row << 10) + (tid << 2)];
  float s = v.x + v.y + v.z + v.w;
  float sq = v.x * v.x + v.y * v.y + v.z * v.z + v.w * v.w;
  float mean = blockSum(s) * (1.f / 1024.f);
  float var = blockSum(sq) * (1.f / 1024.f) - mean * mean;
  float rstd = rsqrtf(fmaxf(var, 0.f) + 1e-5f);
  float vals[4] = {v.x, v.y, v.z, v.w};
  float4 xv = *(float4*)&X[((size_t)row << 10) + (tid << 2)];
  float xa[4] = {xv.x, xv.y, xv.z, xv.w};
#pragma unroll
  for (int i = 0; i < 4; ++i) {
    int c = (tid << 2) + i;
    float y = (vals[i] - mean) * rstd * g[c] + b[c];
    y = y > 0.f ? y : expm1f(y);
    xa[i] += y;
  }
  *(float4*)&X[((size_t)row << 10) + (tid << 2)] = make_float4(xa[0], xa[1], xa[2], xa[3]);
  ushort4 o;
  o.x = f2bf(xa[0]); o.y = f2bf(xa[1]); o.z = f2bf(xa[2]); o.w = f2bf(xa[3]);
  *(ushort4*)&Xb[((size_t)row << 10) + (tid << 2)] = o;
}

// OUT(bf16) = gelu(layernorm(IN))
__global__ __launch_bounds__(256) void ln_gelu(
    const float* __restrict__ IN, u16* __restrict__ OUT,
    const float* __restrict__ g, const float* __restrict__ b) {
  int row = blockIdx.x, tid = threadIdx.x;
  float4 v = *(const float4*)&IN[((size_t)row << 10) + (tid << 2)];
  float s = v.x + v.y + v.z + v.w;
  float sq = v.x * v.x + v.y * v.y + v.z * v.z + v.w * v.w;
  float mean = blockSum(s) * (1.f / 1024.f);
  float var = blockSum(sq) * (1.f / 1024.f) - mean * mean;
  float rstd = rsqrtf(fmaxf(var, 0.f) + 1e-5f);
  float vals[4] = {v.x, v.y, v.z, v.w};
  ushort4 o;
  u16* oa = (u16*)&o;
#pragma unroll
  for (int i = 0; i < 4; ++i) {
    int c = (tid << 2) + i;
    float y = (vals[i] - mean) * rstd * g[c] + b[c];
    y = 0.5f * y * (1.f + erff(y * 0.70710678118654752f));
    oa[i] = f2bf(y);
  }
  *(ushort4*)&OUT[((size_t)row << 10) + (tid << 2)] = o;
}

// OUT(bf16) = l2normalize(IN)
__global__ __launch_bounds__(256) void l2norm_k(const float* __restrict__ IN,
                                                u16* __restrict__ OUT) {
  int row = blockIdx.x, tid = threadIdx.x;
  float4 v = *(const float4*)&IN[((size_t)row << 10) + (tid << 2)];
  float sq = v.x * v.x + v.y * v.y + v.z * v.z + v.w * v.w;
  float s = blockSum(sq);
  float inv = 1.f / fmaxf(sqrtf(s), 1e-12f);
  ushort4 o;
  o.x = f2bf(v.x * inv); o.y = f2bf(v.y * inv);
  o.z = f2bf(v.z * inv); o.w = f2bf(v.w * inv);
  *(ushort4*)&OUT[((size_t)row << 10) + (tid << 2)] = o;
}

__global__ __launch_bounds__(256) void lse_kernel(const float* __restrict__ NEG,
                                                  float* __restrict__ acc) {
  int bq = blockIdx.x, tid = threadIdx.x;
  const float* row = NEG + ((size_t)bq << 10);
  float4 v = *(const float4*)&row[tid << 2];
  float lm = fmaxf(fmaxf(v.x, v.y), fmaxf(v.z, v.w));
  float m = blockMax(lm);
  float ls = expf(v.x - m) + expf(v.y - m) + expf(v.z - m) + expf(v.w - m);
  float ssum = blockSum(ls);
  if (tid == 0) {
    float pos = row[bq];
    float loss = m + logf(ssum + expf(pos - m)) - pos;
    atomicAdd(acc + 1, loss);
  }
}

__global__ __launch_bounds__(256) void dot_reduce(const float* __restrict__ A,
                                                  const float* __restrict__ B,
                                                  float* __restrict__ acc, int n4) {
  int idx = blockIdx.x * blockDim.x + threadIdx.x;
  float s = 0.f;
  for (int i = idx; i < n4; i += gridDim.x * blockDim.x) {
    float4 a = ((const float4*)A)[i];
    float4 b = ((const float4*)B)[i];
    s += a.x * b.x + a.y * b.y + a.z * b.z + a.w * b.w;
  }
  s = blockSum(s);
  if (threadIdx.x == 0) atomicAdd(acc + 0, s);
}

__global__ void final_kernel(const float* __restrict__ acc, float* __restrict__ out) {
  float lap = acc[0] / 2048.f;
  float info = acc[1] / 1024.f;
  out[0] = info + 0.1f * lap;
  out[1] = info;
  out[2] = lap;
}

// ---------------- host launcher ----------------
extern "C" void kernel_launch(void* const* d_in, const int* in_sizes, int n_in,
                              void* d_out, int out_size, void* d_ws, size_t ws_size,
                              hipStream_t stream) {
  const float* query = (const float*)d_in[0];
  const float* docs  = (const float*)d_in[1];
  const float* nodes = (const float*)d_in[2];
  const float* adj   = (const float*)d_in[3];
  const float* lapl  = (const float*)d_in[4];
  const float* qW1 = (const float*)d_in[5],  *qb1 = (const float*)d_in[6];
  const float* qg  = (const float*)d_in[7],  *qbt = (const float*)d_in[8];
  const float* qW2 = (const float*)d_in[9],  *qb2 = (const float*)d_in[10];
  const float* dW1 = (const float*)d_in[11], *db1 = (const float*)d_in[12];
  const float* dg  = (const float*)d_in[13], *dbt = (const float*)d_in[14];
  const float* dW2 = (const float*)d_in[15], *db2 = (const float*)d_in[16];
  const float* gatW = (const float*)d_in[17];
  const float* a1   = (const float*)d_in[18];
  const float* a2   = (const float*)d_in[19];
  const float* ln_g = (const float*)d_in[20];
  const float* ln_b = (const float*)d_in[21];
  const float* poW  = (const float*)d_in[22];
  const float* pob  = (const float*)d_in[23];
  float* out = (float*)d_out;

  float* ws = (float*)d_ws;
  float* S0 = ws + OFF_S0;
  float* S1s = ws + OFF_S1;
  float* S2s = ws + OFF_S2;
  float* S3 = ws + OFF_S3;
  float* S4 = ws + OFF_S4;
  float* S1v = ws + OFF_SV1;
  float* S2v = ws + OFF_SV2;
  float* ACC = ws + OFF_ACC;
  int* NCNT = (int*)(ws + OFF_NCNT);
  int* NBR  = (int*)(ws + OFF_NBR);

  // aliases
  float* X    = S0;
  u16*   laplb= (u16*)S0;
  float* QH   = S0;
  float* PH   = S0 + 1048576;
  float* WH   = S1s;
  float* LG   = S1s;
  u16*   Qb   = (u16*)S1s;
  u16*   Pb   = (u16*)(S1s + 524288);
  u16*   QHb  = (u16*)(S1s + 1048576);
  u16*   PHb  = (u16*)(S1s + 1572864);
  float* HATT = S2s;
  float* G    = S2s;
  u16*   Qnb  = (u16*)S2s;
  u16*   Pnb  = (u16*)(S2s + 524288);
  float* NEG  = S2s + 1048576;
  u16*   WGb  = (u16*)S3;
  u16*   Xb   = (u16*)S4;
  u16*   Gt   = (u16*)S4;

  hipMemsetAsync(ACC, 0, 2 * sizeof(float), stream);
  build_nbr<<<NNODE, 256, 0, stream>>>(adj, NBR, NCNT);
  hipMemcpyAsync(X, nodes, (size_t)NNODE * GH * sizeof(float),
                 hipMemcpyDeviceToDevice, stream);
  cvt_rows<<<2048, 256, 0, stream>>>(nodes, Xb, NNODE * ED / 4);

  for (int l = 0; l < NLAY; ++l) {
    cvt_transpose<<<dim3(2, 16, 8), 256, 0, stream>>>(
        gatW + (size_t)l * NHEAD * ED * HD, WGb, ED, HD, (long)ED * HD, (long)HD * ED);
    gemm_bt2<128><<<dim3(GH / 128, NNODE / 64), 256, 0, stream>>>(
        Xb, WGb, WH, nullptr, NNODE, GH, ED, 1.f);
    s1s2_kernel<<<NNODE * NHEAD, 128, 0, stream>>>(
        WH, a1 + (size_t)l * NHEAD * HD, a2 + (size_t)l * NHEAD * HD, S1v, S2v);
    att_pv<<<NNODE * NHEAD, 128, 0, stream>>>(WH, S1v, S2v, NBR, NCNT, HATT);
    ln_elu_res<<<NNODE, 256, 0, stream>>>(HATT, X, Xb,
        ln_g + (size_t)l * GH, ln_b + (size_t)l * GH);
  }

  // graph embeds + laplacian term
  cvt_transpose<<<dim3(16, 16, 1), 256, 0, stream>>>(poW, WGb, GH, ED, 0, 0);
  gemm_bt2<128><<<dim3(ED / 128, NNODE / 64), 256, 0, stream>>>(
      Xb, WGb, G, pob, NNODE, ED, GH, 1.f);
  cvt_transpose<<<dim3(16, 32, 1), 256, 0, stream>>>(G, Gt, NNODE, ED, 0, 0);
  cvt_rows<<<4096, 256, 0, stream>>>(lapl, laplb, NNODE * NNODE / 4);
  gemm_bt2<128><<<dim3(ED / 128, NNODE / 64), 256, 0, stream>>>(
      laplb, Gt, LG, nullptr, NNODE, ED, NNODE, 1.f);
  dot_reduce<<<512, 256, 0, stream>>>(G, LG, ACC, NNODE * ED / 4);

  // query MLP
  cvt_rows<<<1024, 256, 0, stream>>>(query, Qb, BQ * ED / 4);
  cvt_rows<<<1024, 256, 0, stream>>>(docs, Pb, BQ * ED / 4);
  cvt_transpose<<<dim3(16, 16, 1), 256, 0, stream>>>(qW1, WGb, ED, ED, 0, 0);
  gemm_bt2<64><<<dim3(ED / 64, BQ / 64), 256, 0, stream>>>(
      Qb, WGb, QH, qb1, BQ, ED, ED, 1.f);
  ln_gelu<<<BQ, 256, 0, stream>>>(QH, QHb, qg, qbt);
  cvt_transpose<<<dim3(16, 16, 1), 256, 0, stream>>>(qW2, WGb, ED, ED, 0, 0);
  gemm_bt2<64><<<dim3(ED / 64, BQ / 64), 256, 0, stream>>>(
      QHb, WGb, QH, qb2, BQ, ED, ED, 1.f);
  l2norm_k<<<BQ, 256, 0, stream>>>(QH, Qnb);

  // doc MLP
  cvt_transpose<<<dim3(16, 16, 1), 256, 0, stream>>>(dW1, WGb, ED, ED, 0, 0);
  gemm_bt2<64><<<dim3(ED / 64, BQ / 64), 256, 0, stream>>>(
      Pb, WGb, PH, db1, BQ, ED, ED, 1.f);
  ln_gelu<<<BQ, 256, 0, stream>>>(PH, PHb, dg, dbt);
  cvt_transpose<<<dim3(16, 16, 1), 256, 0, stream>>>(dW2, WGb, ED, ED, 0, 0);
  gemm_bt2<64><<<dim3(ED / 64, BQ / 64), 256, 0, stream>>>(
      PHb, WGb, PH, db2, BQ, ED, ED, 1.f);
  l2norm_k<<<BQ, 256, 0, stream>>>(PH, Pnb);

  // similarities + InfoNCE
  gemm_bt2<64><<<dim3(BQ / 64, BQ / 64), 256, 0, stream>>>(
      Qnb, Pnb, NEG, nullptr, BQ, BQ, ED, 20.f);
  lse_kernel<<<BQ, 256, 0, stream>>>(NEG, ACC);

  final_kernel<<<1, 1, 0, stream>>>(ACC, out);
}

// Round 4
// 517.295 us; speedup vs baseline: 1.3088x; 1.3088x over previous
//
#include <hip/hip_runtime.h>
#include <math.h>

// ---------------- problem constants ----------------
#define ED    1024
#define GH    1024
#define NLAY  3
#define NHEAD 8
#define HD    128
#define NNODE 2048
#define BQ    1024
#define CAP   192

typedef unsigned short u16;
typedef __attribute__((ext_vector_type(8))) short short8;
typedef __attribute__((ext_vector_type(4))) float f32x4;

// ---------------- workspace layout (float units) ----------------
static const size_t OFF_S0  = 0;        // 2M: X fp32 -> laplb bf16 -> QH|PH fp32
static const size_t OFF_S1  = 2097152;  // 2M: WH fp32 -> LG fp32 -> Qb|Pb|QHb|PHb bf16
static const size_t OFF_S2  = 4194304;  // 2M: HATT fp32 -> G fp32 -> Qnb|Pnb bf16 + NEG
static const size_t OFF_S3  = 6291456;  // 0.5M: weight transpose slot A
static const size_t OFF_S4  = 6815744;  // 1M: Xb bf16 -> Gt bf16 -> weight slot B
static const size_t OFF_SV1 = 7864320;
static const size_t OFF_SV2 = 7880704;
static const size_t OFF_ACC = 7897088;
static const size_t OFF_NCNT= 7897096;  // int*
static const size_t OFF_NBR = 7899144;  // int*

// ---------------- helpers ----------------
__device__ __forceinline__ u16 f2bf(float f) {
  unsigned int u = __float_as_uint(f);
  unsigned int r = (u + 0x7fffu + ((u >> 16) & 1u)) >> 16;
  return (u16)r;
}

__device__ __forceinline__ float waveSum(float v) {
#pragma unroll
  for (int off = 32; off; off >>= 1) v += __shfl_xor(v, off, 64);
  return v;
}
__device__ __forceinline__ float waveMax(float v) {
#pragma unroll
  for (int off = 32; off; off >>= 1) v = fmaxf(v, __shfl_xor(v, off, 64));
  return v;
}
__device__ __forceinline__ float blockSum(float v) {
  __shared__ float buf[4];
  int lane = threadIdx.x & 63, wid = threadIdx.x >> 6, nw = (blockDim.x + 63) >> 6;
  v = waveSum(v);
  __syncthreads();
  if (lane == 0) buf[wid] = v;
  __syncthreads();
  float r = buf[0];
  for (int i = 1; i < nw; ++i) r += buf[i];
  return r;
}
__device__ __forceinline__ float blockMax(float v) {
  __shared__ float buf[4];
  int lane = threadIdx.x & 63, wid = threadIdx.x >> 6, nw = (blockDim.x + 63) >> 6;
  v = waveMax(v);
  __syncthreads();
  if (lane == 0) buf[wid] = v;
  __syncthreads();
  float r = buf[0];
  for (int i = 1; i < nw; ++i) r = fmaxf(r, buf[i]);
  return r;
}

// ------------- pipelined 128x128 bf16 MFMA GEMM: C = scale*(A@Bt^T)+bias ----
// A [M,K] bf16 rm. Bt = B0 for rows < split else B1 (both [N,K] bf16 rm).
// C [M,N] fp32. M,N %128==0, K%32==0. 256 thr = 4 waves, each 64x64 (16 MFMA).
// Double-buffered LDS, ONE barrier/iter, register prefetch issued right after
// the barrier and consumed by next iter's ds_write (full-iter latency slack).
// LDS layout lane-linear for writes (conflict-free); frag reads = round-2
// pattern (measured 0 conflicts).
__global__ __launch_bounds__(256) void gemm128(
    const u16* __restrict__ A, const u16* __restrict__ B0,
    const u16* __restrict__ B1, float* __restrict__ C,
    const float* __restrict__ bias0, const float* __restrict__ bias1,
    int M, int N, int K, int split, float scale) {
  __shared__ u16 As[2][128][32];   // 2 x 8 KB
  __shared__ u16 Bs[2][128][32];   // 2 x 8 KB
  const int tid = threadIdx.x, wave = tid >> 6, lane = tid & 63;
  const int bm = blockIdx.y * 128, bn = blockIdx.x * 128;
  const u16* Bt = (bm < split) ? B0 : B1;
  const float* bias = (bm < split) ? bias0 : bias1;

  // staging: thread t covers (row t>>2, seg t&3) and (row (t>>2)+64, seg t&3)
  const int sr = tid >> 2, ss = tid & 3;
  const u16* ga0 = A  + (size_t)(bm + sr) * K + ss * 8;
  const u16* ga1 = A  + (size_t)(bm + sr + 64) * K + ss * 8;
  const u16* gb0 = Bt + (size_t)(bn + sr) * K + ss * 8;
  const u16* gb1 = Bt + (size_t)(bn + sr + 64) * K + ss * 8;

  const int r16 = lane & 15, kg = lane >> 4;
  const int wm = (wave >> 1) * 64, wn = (wave & 1) * 64;

  f32x4 acc[4][4] = {};
  const int nk = K >> 5;

  float4 pa0 = *(const float4*)ga0;
  float4 pa1 = *(const float4*)ga1;
  float4 pb0 = *(const float4*)gb0;
  float4 pb1 = *(const float4*)gb1;

  for (int kt = 0; kt < nk; ++kt) {
    const int p = kt & 1;
    *(float4*)&As[p][sr][ss * 8]      = pa0;
    *(float4*)&As[p][sr + 64][ss * 8] = pa1;
    *(float4*)&Bs[p][sr][ss * 8]      = pb0;
    *(float4*)&Bs[p][sr + 64][ss * 8] = pb1;
    __syncthreads();
    if (kt + 1 < nk) {               // uniform scalar branch
      ga0 += 32; ga1 += 32; gb0 += 32; gb1 += 32;
      pa0 = *(const float4*)ga0;
      pa1 = *(const float4*)ga1;
      pb0 = *(const float4*)gb0;
      pb1 = *(const float4*)gb1;
    }
    short8 av[4], bv[4];
#pragma unroll
    for (int i = 0; i < 4; ++i)
      av[i] = *(const short8*)&As[p][wm + i * 16 + r16][kg * 8];
#pragma unroll
    for (int j = 0; j < 4; ++j)
      bv[j] = *(const short8*)&Bs[p][wn + j * 16 + r16][kg * 8];
#pragma unroll
    for (int i = 0; i < 4; ++i)
#pragma unroll
      for (int j = 0; j < 4; ++j)
        acc[i][j] = __builtin_amdgcn_mfma_f32_16x16x32_bf16(av[i], bv[j], acc[i][j], 0, 0, 0);
    // no second barrier: next iter writes the OTHER buffer; cross-wave safety
    // holds because reads of buf p (iter kt) are issued before barrier(kt+1),
    // and the next write to buf p (iter kt+2) happens after barrier(kt+1).
  }

  // epilogue: C/D layout col=lane&15, row=(lane>>4)*4+reg (m89-verified)
#pragma unroll
  for (int j = 0; j < 4; ++j) {
    int col = bn + wn + j * 16 + r16;
    float bvv = bias ? bias[col] : 0.f;
#pragma unroll
    for (int i = 0; i < 4; ++i) {
      int row0 = bm + wm + i * 16 + kg * 4;
      float* cp = C + (size_t)row0 * N + col;
#pragma unroll
      for (int r = 0; r < 4; ++r)
        cp[(size_t)r * N] = acc[i][j][r] * scale + bvv;
    }
  }
}

// ---------------- conversion kernels ----------------
__global__ __launch_bounds__(256) void cvt_rows(const float* __restrict__ in,
                                                u16* __restrict__ out, int n4) {
  int i = blockIdx.x * 256 + threadIdx.x;
  if (i < n4) {
    float4 v = ((const float4*)in)[i];
    ushort4 o;
    o.x = f2bf(v.x); o.y = f2bf(v.y); o.z = f2bf(v.z); o.w = f2bf(v.w);
    ((ushort4*)out)[i] = o;
  }
}

// in fp32 [R][C] (batch stride inb) -> out bf16 [C][R] (batch stride outb)
__global__ __launch_bounds__(256) void cvt_transpose(
    const float* __restrict__ in, u16* __restrict__ out,
    int R, int C, long inb, long outb) {
  __shared__ float T[64][65];
  const float* ip = in + (size_t)blockIdx.z * inb;
  u16* op = out + (size_t)blockIdx.z * outb;
  int r0 = blockIdx.y * 64, c0 = blockIdx.x * 64;
  int t = threadIdx.x;
#pragma unroll
  for (int p = 0; p < 4; ++p) {
    int row = p * 16 + (t >> 4), col = (t & 15) * 4;
    float4 v = *(const float4*)&ip[(size_t)(r0 + row) * C + c0 + col];
    T[row][col] = v.x; T[row][col + 1] = v.y;
    T[row][col + 2] = v.z; T[row][col + 3] = v.w;
  }
  __syncthreads();
#pragma unroll
  for (int p = 0; p < 4; ++p) {
    int c = p * 16 + (t >> 4), r = (t & 15) * 4;
    ushort4 o;
    o.x = f2bf(T[r][c]); o.y = f2bf(T[r + 1][c]);
    o.z = f2bf(T[r + 2][c]); o.w = f2bf(T[r + 3][c]);
    *(ushort4*)&op[(size_t)(c0 + c) * R + r0 + r] = o;
  }
}

// ---------------- GNN helpers ----------------
__global__ void build_nbr(const float* __restrict__ adj, int* __restrict__ nbr,
                          int* __restrict__ ncnt) {
  __shared__ int cnt;
  int n = blockIdx.x, tid = threadIdx.x;
  if (tid == 0) cnt = 0;
  __syncthreads();
  for (int c = tid; c < NNODE; c += 256) {
    if (adj[((size_t)n << 11) + c] > 0.f) {
      int p = atomicAdd(&cnt, 1);
      if (p < CAP) nbr[n * CAP + p] = c;
    }
  }
  __syncthreads();
  if (tid == 0) ncnt[n] = cnt < CAP ? cnt : CAP;
}

__global__ __launch_bounds__(128) void s1s2_kernel(
    const float* __restrict__ WH, const float* __restrict__ a1l,
    const float* __restrict__ a2l, float* __restrict__ S1, float* __restrict__ S2) {
  __shared__ float b1[2], b2[2];
  int h = blockIdx.x & 7, n = blockIdx.x >> 3;
  int o = threadIdx.x;
  float w = WH[((size_t)n << 10) + (h << 7) + o];
  float p1 = w * a1l[(h << 7) + o];
  float p2 = w * a2l[(h << 7) + o];
  p1 = waveSum(p1); p2 = waveSum(p2);
  int lane = o & 63, wid = o >> 6;
  if (lane == 0) { b1[wid] = p1; b2[wid] = p2; }
  __syncthreads();
  if (o == 0) {
    S1[(h << 11) + n] = b1[0] + b1[1];
    S2[(h << 11) + n] = b2[0] + b2[1];
  }
}

__global__ __launch_bounds__(128) void att_pv(
    const float* __restrict__ WH, const float* __restrict__ S1,
    const float* __restrict__ S2, const int* __restrict__ nbr,
    const int* __restrict__ ncnt, float* __restrict__ HATT) {
  __shared__ float ew[CAP];
  __shared__ int   mi[CAP];
  int h = blockIdx.x & 7, n = blockIdx.x >> 3;
  int tid = threadIdx.x;
  int cnt = ncnt[n];
  float s1v = S1[(h << 11) + n];
  for (int j = tid; j < cnt; j += 128) {
    int m = nbr[n * CAP + j];
    mi[j] = m;
    float e = s1v + S2[(h << 11) + m];
    ew[j] = e > 0.f ? e : 0.2f * e;
  }
  __syncthreads();
  float lmax = -1e30f;
  for (int j = tid; j < cnt; j += 128) lmax = fmaxf(lmax, ew[j]);
  float emax = blockMax(lmax);
  float lsum = 0.f;
  for (int j = tid; j < cnt; j += 128) {
    float w = expf(ew[j] - emax);
    ew[j] = w;
    lsum += w;
  }
  float denom = blockSum(lsum);
  float inv = 1.f / denom;
  int o = tid;
  float acc = 0.f;
  for (int j = 0; j < cnt; ++j)
    acc += ew[j] * WH[((size_t)mi[j] << 10) + (h << 7) + o];
  HATT[((size_t)n << 10) + (h << 7) + o] = acc * inv;
}

// X += elu(layernorm(H)); also writes bf16 shadow Xb
__global__ __launch_bounds__(256) void ln_elu_res(
    const float* __restrict__ H, float* __restrict__ X, u16* __restrict__ Xb,
    const float* __restrict__ g, const float* __restrict__ b) {
  int row = blockIdx.x, tid = threadIdx.x;
  float4 v = *(const float4*)&H[((size_t)row << 10) + (tid << 2)];
  float s = v.x + v.y + v.z + v.w;
  float sq = v.x * v.x + v.y * v.y + v.z * v.z + v.w * v.w;
  float mean = blockSum(s) * (1.f / 1024.f);
  float var = blockSum(sq) * (1.f / 1024.f) - mean * mean;
  float rstd = rsqrtf(fmaxf(var, 0.f) + 1e-5f);
  float vals[4] = {v.x, v.y, v.z, v.w};
  float4 xv = *(float4*)&X[((size_t)row << 10) + (tid << 2)];
  float xa[4] = {xv.x, xv.y, xv.z, xv.w};
#pragma unroll
  for (int i = 0; i < 4; ++i) {
    int c = (tid << 2) + i;
    float y = (vals[i] - mean) * rstd * g[c] + b[c];
    y = y > 0.f ? y : expm1f(y);
    xa[i] += y;
  }
  *(float4*)&X[((size_t)row << 10) + (tid << 2)] = make_float4(xa[0], xa[1], xa[2], xa[3]);
  ushort4 o;
  o.x = f2bf(xa[0]); o.y = f2bf(xa[1]); o.z = f2bf(xa[2]); o.w = f2bf(xa[3]);
  *(ushort4*)&Xb[((size_t)row << 10) + (tid << 2)] = o;
}

// OUT(bf16) = gelu(layernorm(IN)); rows<1024 use g0/b0 else g1/b1
__global__ __launch_bounds__(256) void ln_gelu(
    const float* __restrict__ IN, u16* __restrict__ OUT,
    const float* __restrict__ g0, const float* __restrict__ b0,
    const float* __restrict__ g1, const float* __restrict__ b1) {
  int row = blockIdx.x, tid = threadIdx.x;
  const float* g = (row < 1024) ? g0 : g1;
  const float* b = (row < 1024) ? b0 : b1;
  float4 v = *(const float4*)&IN[((size_t)row << 10) + (tid << 2)];
  float s = v.x + v.y + v.z + v.w;
  float sq = v.x * v.x + v.y * v.y + v.z * v.z + v.w * v.w;
  float mean = blockSum(s) * (1.f / 1024.f);
  float var = blockSum(sq) * (1.f / 1024.f) - mean * mean;
  float rstd = rsqrtf(fmaxf(var, 0.f) + 1e-5f);
  float vals[4] = {v.x, v.y, v.z, v.w};
  ushort4 o;
  u16* oa = (u16*)&o;
#pragma unroll
  for (int i = 0; i < 4; ++i) {
    int c = (tid << 2) + i;
    float y = (vals[i] - mean) * rstd * g[c] + b[c];
    y = 0.5f * y * (1.f + erff(y * 0.70710678118654752f));
    oa[i] = f2bf(y);
  }
  *(ushort4*)&OUT[((size_t)row << 10) + (tid << 2)] = o;
}

// OUT(bf16) = l2normalize(IN)
__global__ __launch_bounds__(256) void l2norm_k(const float* __restrict__ IN,
                                                u16* __restrict__ OUT) {
  int row = blockIdx.x, tid = threadIdx.x;
  float4 v = *(const float4*)&IN[((size_t)row << 10) + (tid << 2)];
  float sq = v.x * v.x + v.y * v.y + v.z * v.z + v.w * v.w;
  float s = blockSum(sq);
  float inv = 1.f / fmaxf(sqrtf(s), 1e-12f);
  ushort4 o;
  o.x = f2bf(v.x * inv); o.y = f2bf(v.y * inv);
  o.z = f2bf(v.z * inv); o.w = f2bf(v.w * inv);
  *(ushort4*)&OUT[((size_t)row << 10) + (tid << 2)] = o;
}

__global__ __launch_bounds__(256) void lse_kernel(const float* __restrict__ NEG,
                                                  float* __restrict__ acc) {
  int bq = blockIdx.x, tid = threadIdx.x;
  const float* row = NEG + ((size_t)bq << 10);
  float4 v = *(const float4*)&row[tid << 2];
  float lm = fmaxf(fmaxf(v.x, v.y), fmaxf(v.z, v.w));
  float m = blockMax(lm);
  float ls = expf(v.x - m) + expf(v.y - m) + expf(v.z - m) + expf(v.w - m);
  float ssum = blockSum(ls);
  if (tid == 0) {
    float pos = row[bq];
    float loss = m + logf(ssum + expf(pos - m)) - pos;
    atomicAdd(acc + 1, loss);
  }
}

__global__ __launch_bounds__(256) void dot_reduce(const float* __restrict__ A,
                                                  const float* __restrict__ B,
                                                  float* __restrict__ acc, int n4) {
  int idx = blockIdx.x * blockDim.x + threadIdx.x;
  float s = 0.f;
  for (int i = idx; i < n4; i += gridDim.x * blockDim.x) {
    float4 a = ((const float4*)A)[i];
    float4 b = ((const float4*)B)[i];
    s += a.x * b.x + a.y * b.y + a.z * b.z + a.w * b.w;
  }
  s = blockSum(s);
  if (threadIdx.x == 0) atomicAdd(acc + 0, s);
}

__global__ void final_kernel(const float* __restrict__ acc, float* __restrict__ out) {
  float lap = acc[0] / 2048.f;
  float info = acc[1] / 1024.f;
  out[0] = info + 0.1f * lap;
  out[1] = info;
  out[2] = lap;
}

// ---------------- host launcher ----------------
extern "C" void kernel_launch(void* const* d_in, const int* in_sizes, int n_in,
                              void* d_out, int out_size, void* d_ws, size_t ws_size,
                              hipStream_t stream) {
  const float* query = (const float*)d_in[0];
  const float* docs  = (const float*)d_in[1];
  const float* nodes = (const float*)d_in[2];
  const float* adj   = (const float*)d_in[3];
  const float* lapl  = (const float*)d_in[4];
  const float* qW1 = (const float*)d_in[5],  *qb1 = (const float*)d_in[6];
  const float* qg  = (const float*)d_in[7],  *qbt = (const float*)d_in[8];
  const float* qW2 = (const float*)d_in[9],  *qb2 = (const float*)d_in[10];
  const float* dW1 = (const float*)d_in[11], *db1 = (const float*)d_in[12];
  const float* dg  = (const float*)d_in[13], *dbt = (const float*)d_in[14];
  const float* dW2 = (const float*)d_in[15], *db2 = (const float*)d_in[16];
  const float* gatW = (const float*)d_in[17];
  const float* a1   = (const float*)d_in[18];
  const float* a2   = (const float*)d_in[19];
  const float* ln_g = (const float*)d_in[20];
  const float* ln_b = (const float*)d_in[21];
  const float* poW  = (const float*)d_in[22];
  const float* pob  = (const float*)d_in[23];
  float* out = (float*)d_out;

  float* ws = (float*)d_ws;
  float* S0 = ws + OFF_S0;
  float* S1s = ws + OFF_S1;
  float* S2s = ws + OFF_S2;
  float* S3 = ws + OFF_S3;
  float* S4 = ws + OFF_S4;
  float* S1v = ws + OFF_SV1;
  float* S2v = ws + OFF_SV2;
  float* ACC = ws + OFF_ACC;
  int* NCNT = (int*)(ws + OFF_NCNT);
  int* NBR  = (int*)(ws + OFF_NBR);

  // aliases (stream-ordered reuse)
  float* X    = S0;                       // GNN fp32 state
  u16*   laplb= (u16*)S0;                 // [2048][2048] bf16 after X is dead
  float* QP   = S0;                       // [2048][1024] fp32 MLP activations (q|d)
  float* WH   = S1s;                      // [2048][1024] fp32
  float* LG   = S1s;                      // lapl @ G fp32
  u16*   Qb   = (u16*)S1s;                // [1024][1024] bf16  (q|d contiguous)
  u16*   QHb  = (u16*)(S1s + 1048576);    // [2048][1024] bf16 hidden (q|d)
  float* HATT = S2s;
  float* G    = S2s;
  u16*   Qnb  = (u16*)S2s;                // [2048][1024] bf16 normalized (q|d)
  float* NEG  = S2s + 1048576;
  u16*   WTA  = (u16*)S3;                 // weight transpose slot A
  u16*   Xb   = (u16*)S4;                 // bf16 shadow of X
  u16*   Gt   = (u16*)S4;                 // G^T bf16 (after Xb dead)
  u16*   WTB  = (u16*)S4;                 // weight transpose slot B (after Gt dead)
  u16*   Pnb  = Qnb + 1048576;

  hipMemsetAsync(ACC, 0, 2 * sizeof(float), stream);
  build_nbr<<<NNODE, 256, 0, stream>>>(adj, NBR, NCNT);
  hipMemcpyAsync(X, nodes, (size_t)NNODE * GH * sizeof(float),
                 hipMemcpyDeviceToDevice, stream);
  cvt_rows<<<2048, 256, 0, stream>>>(nodes, Xb, NNODE * ED / 4);

  for (int l = 0; l < NLAY; ++l) {
    cvt_transpose<<<dim3(2, 16, 8), 256, 0, stream>>>(
        gatW + (size_t)l * NHEAD * ED * HD, WTA, ED, HD, (long)ED * HD, (long)HD * ED);
    gemm128<<<dim3(GH / 128, NNODE / 128), 256, 0, stream>>>(
        Xb, WTA, WTA, WH, nullptr, nullptr, NNODE, GH, ED, NNODE, 1.f);
    s1s2_kernel<<<NNODE * NHEAD, 128, 0, stream>>>(
        WH, a1 + (size_t)l * NHEAD * HD, a2 + (size_t)l * NHEAD * HD, S1v, S2v);
    att_pv<<<NNODE * NHEAD, 128, 0, stream>>>(WH, S1v, S2v, NBR, NCNT, HATT);
    ln_elu_res<<<NNODE, 256, 0, stream>>>(HATT, X, Xb,
        ln_g + (size_t)l * GH, ln_b + (size_t)l * GH);
  }

  // graph embeds + laplacian term
  cvt_transpose<<<dim3(16, 16, 1), 256, 0, stream>>>(poW, WTA, GH, ED, 0, 0);
  gemm128<<<dim3(ED / 128, NNODE / 128), 256, 0, stream>>>(
      Xb, WTA, WTA, G, pob, pob, NNODE, ED, GH, NNODE, 1.f);
  cvt_transpose<<<dim3(16, 32, 1), 256, 0, stream>>>(G, Gt, NNODE, ED, 0, 0);
  cvt_rows<<<4096, 256, 0, stream>>>(lapl, laplb, NNODE * NNODE / 4);
  gemm128<<<dim3(ED / 128, NNODE / 128), 256, 0, stream>>>(
      laplb, Gt, Gt, LG, nullptr, nullptr, NNODE, ED, NNODE, NNODE, 1.f);
  dot_reduce<<<512, 256, 0, stream>>>(G, LG, ACC, NNODE * ED / 4);

  // fused q|d MLP (batched rows: 0-1023 = query, 1024-2047 = docs)
  cvt_rows<<<1024, 256, 0, stream>>>(query, Qb, BQ * ED / 4);
  cvt_rows<<<1024, 256, 0, stream>>>(docs, Qb + BQ * ED, BQ * ED / 4);
  cvt_transpose<<<dim3(16, 16, 1), 256, 0, stream>>>(qW1, WTA, ED, ED, 0, 0);
  cvt_transpose<<<dim3(16, 16, 1), 256, 0, stream>>>(dW1, WTB, ED, ED, 0, 0);
  gemm128<<<dim3(ED / 128, 2 * BQ / 128), 256, 0, stream>>>(
      Qb, WTA, WTB, QP, qb1, db1, 2 * BQ, ED, ED, BQ, 1.f);
  ln_gelu<<<2 * BQ, 256, 0, stream>>>(QP, QHb, qg, qbt, dg, dbt);
  cvt_transpose<<<dim3(16, 16, 1), 256, 0, stream>>>(qW2, WTA, ED, ED, 0, 0);
  cvt_transpose<<<dim3(16, 16, 1), 256, 0, stream>>>(dW2, WTB, ED, ED, 0, 0);
  gemm128<<<dim3(ED / 128, 2 * BQ / 128), 256, 0, stream>>>(
      QHb, WTA, WTB, QP, qb2, db2, 2 * BQ, ED, ED, BQ, 1.f);
  l2norm_k<<<2 * BQ, 256, 0, stream>>>(QP, Qnb);

  // similarities + InfoNCE
  gemm128<<<dim3(BQ / 128, BQ / 128), 256, 0, stream>>>(
      Qnb, Pnb, Pnb, NEG, nullptr, nullptr, BQ, BQ, ED, BQ, 20.f);
  lse_kernel<<<BQ, 256, 0, stream>>>(NEG, ACC);

  final_kernel<<<1, 1, 0, stream>>>(ACC, out);
}

// Round 5
// 497.265 us; speedup vs baseline: 1.3615x; 1.0403x over previous
//
#include <hip/hip_runtime.h>
#include <math.h>

// ---------------- problem constants ----------------
#define ED    1024
#define GH    1024
#define NLAY  3
#define NHEAD 8
#define HD    128
#define NNODE 2048
#define BQ    1024
#define CAP   192

typedef unsigned short u16;
typedef __attribute__((ext_vector_type(8))) short short8;
typedef __attribute__((ext_vector_type(4))) float f32x4;

// ---------------- workspace layout (float units); ws_size ~268MB, use ~69MB --
static const size_t OFF_X    = 0;         // [2048][1024] fp32 GNN state
static const size_t OFF_XB   = 2097152;   // [2048][1024] bf16 shadow
static const size_t OFF_WHB  = 3145728;   // [2048][1024] bf16 Wh
static const size_t OFF_WTA  = 4194304;   // [1024][1024] bf16 weight^T slot A
static const size_t OFF_WTB  = 4718592;   // [1024][1024] bf16 weight^T slot B
static const size_t OFF_G    = 5242880;   // [2048][1024] fp32 graph embeds
static const size_t OFF_GT   = 7340032;   // [1024][2048] bf16 G^T
static const size_t OFF_QPB  = 8388608;   // [2048][1024] bf16 q|d inputs
static const size_t OFF_HF   = 9437184;   // [2048][1024] fp32 MLP hidden
static const size_t OFF_HB   = 11534336;  // [2048][1024] bf16
static const size_t OFF_FF   = 12582912;  // [2048][1024] fp32 MLP out
static const size_t OFF_FB   = 14680064;  // [2048][1024] bf16 normalized
static const size_t OFF_NEG  = 15728640;  // [1024][1024] fp32 logits
static const size_t OFF_ACC  = 16777216;  // [0]=lap [1]=nce
static const size_t OFF_NCNT = 16777224;  // 2048 ints
static const size_t OFF_NBR  = 16779272;  // 2048*CAP ints

// ---------------- helpers ----------------
__device__ __forceinline__ u16 f2bf(float f) {
  unsigned int u = __float_as_uint(f);
  return (u16)((u + 0x7fffu + ((u >> 16) & 1u)) >> 16);
}
__device__ __forceinline__ float bf2f(u16 u) {
  return __uint_as_float(((unsigned int)u) << 16);
}

__device__ __forceinline__ float waveSum(float v) {
#pragma unroll
  for (int off = 32; off; off >>= 1) v += __shfl_xor(v, off, 64);
  return v;
}
__device__ __forceinline__ float waveMax(float v) {
#pragma unroll
  for (int off = 32; off; off >>= 1) v = fmaxf(v, __shfl_xor(v, off, 64));
  return v;
}
__device__ __forceinline__ float blockSum(float v) {
  __shared__ float buf[4];
  int lane = threadIdx.x & 63, wid = threadIdx.x >> 6, nw = (blockDim.x + 63) >> 6;
  v = waveSum(v);
  __syncthreads();
  if (lane == 0) buf[wid] = v;
  __syncthreads();
  float r = buf[0];
  for (int i = 1; i < nw; ++i) r += buf[i];
  return r;
}
__device__ __forceinline__ float blockMax(float v) {
  __shared__ float buf[4];
  int lane = threadIdx.x & 63, wid = threadIdx.x >> 6, nw = (blockDim.x + 63) >> 6;
  v = waveMax(v);
  __syncthreads();
  if (lane == 0) buf[wid] = v;
  __syncthreads();
  float r = buf[0];
  for (int i = 1; i < nw; ++i) r = fmaxf(r, buf[i]);
  return r;
}

// ------------- pipelined 128x128 bf16 MFMA GEMM (round-4 core, verified) ----
// A [M,K] bf16 rm. Bt = B0 for rows<split else B1 ([N,K] bf16 rm).
// Outputs: C fp32 (nullable) and/or Cb bf16 (nullable), both = scale*AB + bias.
__global__ __launch_bounds__(256) void gemm128(
    const u16* __restrict__ A, const u16* __restrict__ B0,
    const u16* __restrict__ B1, float* __restrict__ C, u16* __restrict__ Cb,
    const float* __restrict__ bias0, const float* __restrict__ bias1,
    int M, int N, int K, int split, float scale) {
  __shared__ u16 As[2][128][32];
  __shared__ u16 Bs[2][128][32];
  const int tid = threadIdx.x, wave = tid >> 6, lane = tid & 63;
  const int bm = blockIdx.y * 128, bn = blockIdx.x * 128;
  const u16* Bt = (bm < split) ? B0 : B1;
  const float* bias = (bm < split) ? bias0 : bias1;

  const int sr = tid >> 2, ss = tid & 3;
  const u16* ga0 = A  + (size_t)(bm + sr) * K + ss * 8;
  const u16* ga1 = A  + (size_t)(bm + sr + 64) * K + ss * 8;
  const u16* gb0 = Bt + (size_t)(bn + sr) * K + ss * 8;
  const u16* gb1 = Bt + (size_t)(bn + sr + 64) * K + ss * 8;

  const int r16 = lane & 15, kg = lane >> 4;
  const int wm = (wave >> 1) * 64, wn = (wave & 1) * 64;

  f32x4 acc[4][4] = {};
  const int nk = K >> 5;

  float4 pa0 = *(const float4*)ga0;
  float4 pa1 = *(const float4*)ga1;
  float4 pb0 = *(const float4*)gb0;
  float4 pb1 = *(const float4*)gb1;

  for (int kt = 0; kt < nk; ++kt) {
    const int p = kt & 1;
    *(float4*)&As[p][sr][ss * 8]      = pa0;
    *(float4*)&As[p][sr + 64][ss * 8] = pa1;
    *(float4*)&Bs[p][sr][ss * 8]      = pb0;
    *(float4*)&Bs[p][sr + 64][ss * 8] = pb1;
    __syncthreads();
    if (kt + 1 < nk) {
      ga0 += 32; ga1 += 32; gb0 += 32; gb1 += 32;
      pa0 = *(const float4*)ga0;
      pa1 = *(const float4*)ga1;
      pb0 = *(const float4*)gb0;
      pb1 = *(const float4*)gb1;
    }
    short8 av[4], bv[4];
#pragma unroll
    for (int i = 0; i < 4; ++i)
      av[i] = *(const short8*)&As[p][wm + i * 16 + r16][kg * 8];
#pragma unroll
    for (int j = 0; j < 4; ++j)
      bv[j] = *(const short8*)&Bs[p][wn + j * 16 + r16][kg * 8];
#pragma unroll
    for (int i = 0; i < 4; ++i)
#pragma unroll
      for (int j = 0; j < 4; ++j)
        acc[i][j] = __builtin_amdgcn_mfma_f32_16x16x32_bf16(av[i], bv[j], acc[i][j], 0, 0, 0);
  }

  // epilogue: C/D layout col=lane&15, row=(lane>>4)*4+reg (m89-verified)
  if (C) {
#pragma unroll
    for (int j = 0; j < 4; ++j) {
      int col = bn + wn + j * 16 + r16;
      float bvv = bias ? bias[col] : 0.f;
#pragma unroll
      for (int i = 0; i < 4; ++i) {
        int row0 = bm + wm + i * 16 + kg * 4;
        float* cp = C + (size_t)row0 * N + col;
#pragma unroll
        for (int r = 0; r < 4; ++r)
          cp[(size_t)r * N] = acc[i][j][r] * scale + bvv;
      }
    }
  }
  if (Cb) {
#pragma unroll
    for (int j = 0; j < 4; ++j) {
      int col = bn + wn + j * 16 + r16;
      float bvv = bias ? bias[col] : 0.f;
#pragma unroll
      for (int i = 0; i < 4; ++i) {
        int row0 = bm + wm + i * 16 + kg * 4;
        u16* cp = Cb + (size_t)row0 * N + col;
#pragma unroll
        for (int r = 0; r < 4; ++r)
          cp[(size_t)r * N] = f2bf(acc[i][j][r] * scale + bvv);
      }
    }
  }
}

// ------------- lap GEMM: partial (lapl @ Gt^T) tile, fused dot with G -------
// A=lapl fp32 [2048][2048] (converted to bf16 on the fly during staging),
// Bt=Gt bf16 [1024][2048]. Split-K via blockIdx.z (2 halves of 1024).
// Epilogue: sum(tile * G_tile) -> atomicAdd(acc_out).
__global__ __launch_bounds__(256) void lap_gemm(
    const float* __restrict__ A, const u16* __restrict__ Bt,
    const float* __restrict__ G, float* __restrict__ acc_out) {
  __shared__ u16 As[2][128][32];
  __shared__ u16 Bs[2][128][32];
  const int tid = threadIdx.x, wave = tid >> 6, lane = tid & 63;
  const int bm = blockIdx.y * 128, bn = blockIdx.x * 128;
  const int k0 = blockIdx.z * 1024;

  // A staging: thread t -> row t>>1, 16-float seg (t&1)
  const int ar = tid >> 1, asg = (tid & 1) * 16;
  const float* gA = A + (size_t)(bm + ar) * NNODE + k0 + asg;
  // B staging: as gemm128
  const int sr = tid >> 2, ss = tid & 3;
  const u16* gb0 = Bt + (size_t)(bn + sr) * NNODE + k0 + ss * 8;
  const u16* gb1 = Bt + (size_t)(bn + sr + 64) * NNODE + k0 + ss * 8;

  const int r16 = lane & 15, kg = lane >> 4;
  const int wm = (wave >> 1) * 64, wn = (wave & 1) * 64;

  f32x4 acc[4][4] = {};
  const int nk = 32;

  float4 pa[4], pb0, pb1;
#pragma unroll
  for (int u = 0; u < 4; ++u) pa[u] = *(const float4*)(gA + u * 4);
  pb0 = *(const float4*)gb0;
  pb1 = *(const float4*)gb1;

  for (int kt = 0; kt < nk; ++kt) {
    const int p = kt & 1;
#pragma unroll
    for (int u = 0; u < 4; ++u) {
      ushort4 o;
      o.x = f2bf(pa[u].x); o.y = f2bf(pa[u].y);
      o.z = f2bf(pa[u].z); o.w = f2bf(pa[u].w);
      *(ushort4*)&As[p][ar][asg + u * 4] = o;
    }
    *(float4*)&Bs[p][sr][ss * 8]      = pb0;
    *(float4*)&Bs[p][sr + 64][ss * 8] = pb1;
    __syncthreads();
    if (kt + 1 < nk) {
      gA += 32; gb0 += 32; gb1 += 32;
#pragma unroll
      for (int u = 0; u < 4; ++u) pa[u] = *(const float4*)(gA + u * 4);
      pb0 = *(const float4*)gb0;
      pb1 = *(const float4*)gb1;
    }
    short8 av[4], bv[4];
#pragma unroll
    for (int i = 0; i < 4; ++i)
      av[i] = *(const short8*)&As[p][wm + i * 16 + r16][kg * 8];
#pragma unroll
    for (int j = 0; j < 4; ++j)
      bv[j] = *(const short8*)&Bs[p][wn + j * 16 + r16][kg * 8];
#pragma unroll
    for (int i = 0; i < 4; ++i)
#pragma unroll
      for (int j = 0; j < 4; ++j)
        acc[i][j] = __builtin_amdgcn_mfma_f32_16x16x32_bf16(av[i], bv[j], acc[i][j], 0, 0, 0);
  }

  float sum = 0.f;
#pragma unroll
  for (int j = 0; j < 4; ++j) {
    int col = bn + wn + j * 16 + r16;
#pragma unroll
    for (int i = 0; i < 4; ++i) {
      int row0 = bm + wm + i * 16 + kg * 4;
      const float* gp = G + (size_t)row0 * ED + col;
#pragma unroll
      for (int r = 0; r < 4; ++r)
        sum += acc[i][j][r] * gp[(size_t)r * ED];
    }
  }
  sum = blockSum(sum);
  if (tid == 0) atomicAdd(acc_out, sum);
}

// ------------- fused GAT attention + LN + elu + residual --------------------
// One block per node, 256 threads (32 per head). Online softmax over the
// sparse neighbor list; PV gather from bf16 WHb; LN over GH in-block.
__global__ __launch_bounds__(256) void fused_att(
    const u16* __restrict__ WHb, const float* __restrict__ a1l,
    const float* __restrict__ a2l, const int* __restrict__ nbr,
    const int* __restrict__ ncnt, float* __restrict__ X, u16* __restrict__ Xb,
    const float* __restrict__ g, const float* __restrict__ b) {
  __shared__ int snb[CAP];
  const int n = blockIdx.x, t = threadIdx.x;
  const int cnt = ncnt[n];
  for (int j = t; j < cnt; j += 256) snb[j] = nbr[n * CAP + j];

  const float4 a1v = *(const float4*)(a1l + (t << 2));
  const float4 a2v = *(const float4*)(a2l + (t << 2));

  // s1 for this node's head
  ushort4 w0 = *(const ushort4*)(WHb + ((size_t)n << 10) + (t << 2));
  float s1 = bf2f(w0.x) * a1v.x + bf2f(w0.y) * a1v.y +
             bf2f(w0.z) * a1v.z + bf2f(w0.w) * a1v.w;
#pragma unroll
  for (int off = 16; off; off >>= 1) s1 += __shfl_xor(s1, off, 64);

  __syncthreads();   // snb ready

  float mh = -1e30f, lh = 0.f;
  float ac0 = 0.f, ac1 = 0.f, ac2 = 0.f, ac3 = 0.f;
  ushort4 wx = *(const ushort4*)(WHb + ((size_t)snb[0] << 10) + (t << 2));
  for (int j = 0; j < cnt; ++j) {
    float v0 = bf2f(wx.x), v1 = bf2f(wx.y), v2 = bf2f(wx.z), v3 = bf2f(wx.w);
    if (j + 1 < cnt)
      wx = *(const ushort4*)(WHb + ((size_t)snb[j + 1] << 10) + (t << 2));
    float s2 = v0 * a2v.x + v1 * a2v.y + v2 * a2v.z + v3 * a2v.w;
#pragma unroll
    for (int off = 16; off; off >>= 1) s2 += __shfl_xor(s2, off, 64);
    float e = s1 + s2;
    e = e > 0.f ? e : 0.2f * e;                 // leaky_relu 0.2
    float nm = fmaxf(mh, e);
    float al = __expf(mh - nm);
    float p  = __expf(e - nm);
    lh = lh * al + p;
    ac0 = ac0 * al + p * v0;
    ac1 = ac1 * al + p * v1;
    ac2 = ac2 * al + p * v2;
    ac3 = ac3 * al + p * v3;
    mh = nm;
  }
  float inv = 1.f / lh;
  float o0 = ac0 * inv, o1 = ac1 * inv, o2 = ac2 * inv, o3 = ac3 * inv;

  // LN over 1024 dims + elu + residual
  float s  = o0 + o1 + o2 + o3;
  float sq = o0 * o0 + o1 * o1 + o2 * o2 + o3 * o3;
  float mean = blockSum(s) * (1.f / 1024.f);
  float var  = blockSum(sq) * (1.f / 1024.f) - mean * mean;
  float rstd = rsqrtf(fmaxf(var, 0.f) + 1e-5f);
  float4 xv = *(float4*)&X[((size_t)n << 10) + (t << 2)];
  float ov[4] = {o0, o1, o2, o3};
  float xa[4] = {xv.x, xv.y, xv.z, xv.w};
#pragma unroll
  for (int i = 0; i < 4; ++i) {
    int c = (t << 2) + i;
    float y = (ov[i] - mean) * rstd * g[c] + b[c];
    y = y > 0.f ? y : expm1f(y);
    xa[i] += y;
  }
  *(float4*)&X[((size_t)n << 10) + (t << 2)] = make_float4(xa[0], xa[1], xa[2], xa[3]);
  ushort4 o;
  o.x = f2bf(xa[0]); o.y = f2bf(xa[1]); o.z = f2bf(xa[2]); o.w = f2bf(xa[3]);
  *(ushort4*)&Xb[((size_t)n << 10) + (t << 2)] = o;
}

// ---------------- small kernels ----------------
__global__ void build_nbr(const float* __restrict__ adj, int* __restrict__ nbr,
                          int* __restrict__ ncnt) {
  __shared__ int cnt;
  int n = blockIdx.x, tid = threadIdx.x;
  if (tid == 0) cnt = 0;
  __syncthreads();
  for (int c = tid; c < NNODE; c += 256) {
    if (adj[((size_t)n << 11) + c] > 0.f) {
      int p = atomicAdd(&cnt, 1);
      if (p < CAP) nbr[n * CAP + p] = c;
    }
  }
  __syncthreads();
  if (tid == 0) ncnt[n] = cnt < CAP ? cnt : CAP;
}

// nodes -> X fp32 copy + Xb bf16 shadow
__global__ __launch_bounds__(256) void cvt_dual(const float* __restrict__ in,
                                                float* __restrict__ Xf,
                                                u16* __restrict__ Xb) {
  int i = blockIdx.x * 256 + threadIdx.x;
  float4 v = ((const float4*)in)[i];
  ((float4*)Xf)[i] = v;
  ushort4 o;
  o.x = f2bf(v.x); o.y = f2bf(v.y); o.z = f2bf(v.z); o.w = f2bf(v.w);
  ((ushort4*)Xb)[i] = o;
}

// query|docs -> QPb bf16 (2048 rows)
__global__ __launch_bounds__(256) void qd_cvt(const float* __restrict__ q,
                                              const float* __restrict__ d,
                                              u16* __restrict__ out) {
  int i = blockIdx.x * 256 + threadIdx.x;          // [0, 2*262144)
  const int half = BQ * ED / 4;
  const float* src = (i < half) ? q : d;
  int j = (i < half) ? i : i - half;
  float4 v = ((const float4*)src)[j];
  ushort4 o;
  o.x = f2bf(v.x); o.y = f2bf(v.y); o.z = f2bf(v.z); o.w = f2bf(v.w);
  ((ushort4*)out)[i] = o;
}

// in fp32 [R][C] (batch stride inb) -> out bf16 [C][R] (batch stride outb)
__global__ __launch_bounds__(256) void cvt_transpose(
    const float* __restrict__ in, u16* __restrict__ out,
    int R, int C, long inb, long outb) {
  __shared__ float T[64][65];
  const float* ip = in + (size_t)blockIdx.z * inb;
  u16* op = out + (size_t)blockIdx.z * outb;
  int r0 = blockIdx.y * 64, c0 = blockIdx.x * 64;
  int t = threadIdx.x;
#pragma unroll
  for (int p = 0; p < 4; ++p) {
    int row = p * 16 + (t >> 4), col = (t & 15) * 4;
    float4 v = *(const float4*)&ip[(size_t)(r0 + row) * C + c0 + col];
    T[row][col] = v.x; T[row][col + 1] = v.y;
    T[row][col + 2] = v.z; T[row][col + 3] = v.w;
  }
  __syncthreads();
#pragma unroll
  for (int p = 0; p < 4; ++p) {
    int c = p * 16 + (t >> 4), r = (t & 15) * 4;
    ushort4 o;
    o.x = f2bf(T[r][c]); o.y = f2bf(T[r + 1][c]);
    o.z = f2bf(T[r + 2][c]); o.w = f2bf(T[r + 3][c]);
    *(ushort4*)&op[(size_t)(c0 + c) * R + r0 + r] = o;
  }
}

// OUT(bf16) = gelu(layernorm(IN)); rows<1024 use g0/b0 else g1/b1
__global__ __launch_bounds__(256) void ln_gelu(
    const float* __restrict__ IN, u16* __restrict__ OUT,
    const float* __restrict__ g0, const float* __restrict__ b0,
    const float* __restrict__ g1, const float* __restrict__ b1) {
  int row = blockIdx.x, tid = threadIdx.x;
  const float* g = (row < 1024) ? g0 : g1;
  const float* b = (row < 1024) ? b0 : b1;
  float4 v = *(const float4*)&IN[((size_t)row << 10) + (tid << 2)];
  float s = v.x + v.y + v.z + v.w;
  float sq = v.x * v.x + v.y * v.y + v.z * v.z + v.w * v.w;
  float mean = blockSum(s) * (1.f / 1024.f);
  float var = blockSum(sq) * (1.f / 1024.f) - mean * mean;
  float rstd = rsqrtf(fmaxf(var, 0.f) + 1e-5f);
  float vals[4] = {v.x, v.y, v.z, v.w};
  ushort4 o;
  u16* oa = (u16*)&o;
#pragma unroll
  for (int i = 0; i < 4; ++i) {
    int c = (tid << 2) + i;
    float y = (vals[i] - mean) * rstd * g[c] + b[c];
    y = 0.5f * y * (1.f + erff(y * 0.70710678118654752f));
    oa[i] = f2bf(y);
  }
  *(ushort4*)&OUT[((size_t)row << 10) + (tid << 2)] = o;
}

// OUT(bf16) = l2normalize(IN)
__global__ __launch_bounds__(256) void l2norm_k(const float* __restrict__ IN,
                                                u16* __restrict__ OUT) {
  int row = blockIdx.x, tid = threadIdx.x;
  float4 v = *(const float4*)&IN[((size_t)row << 10) + (tid << 2)];
  float sq = v.x * v.x + v.y * v.y + v.z * v.z + v.w * v.w;
  float s = blockSum(sq);
  float inv = 1.f / fmaxf(sqrtf(s), 1e-12f);
  ushort4 o;
  o.x = f2bf(v.x * inv); o.y = f2bf(v.y * inv);
  o.z = f2bf(v.z * inv); o.w = f2bf(v.w * inv);
  *(ushort4*)&OUT[((size_t)row << 10) + (tid << 2)] = o;
}

__global__ __launch_bounds__(256) void lse_kernel(const float* __restrict__ NEG,
                                                  float* __restrict__ acc) {
  int bq = blockIdx.x, tid = threadIdx.x;
  const float* row = NEG + ((size_t)bq << 10);
  float4 v = *(const float4*)&row[tid << 2];
  float lm = fmaxf(fmaxf(v.x, v.y), fmaxf(v.z, v.w));
  float m = blockMax(lm);
  float ls = __expf(v.x - m) + __expf(v.y - m) + __expf(v.z - m) + __expf(v.w - m);
  float ssum = blockSum(ls);
  if (tid == 0) {
    float pos = row[bq];
    float loss = m + logf(ssum + __expf(pos - m)) - pos;
    atomicAdd(acc + 1, loss);
  }
}

__global__ void final_kernel(const float* __restrict__ acc, float* __restrict__ out) {
  float lap = acc[0] / 2048.f;
  float info = acc[1] / 1024.f;
  out[0] = info + 0.1f * lap;
  out[1] = info;
  out[2] = lap;
}

// ---------------- host launcher ----------------
extern "C" void kernel_launch(void* const* d_in, const int* in_sizes, int n_in,
                              void* d_out, int out_size, void* d_ws, size_t ws_size,
                              hipStream_t stream) {
  const float* query = (const float*)d_in[0];
  const float* docs  = (const float*)d_in[1];
  const float* nodes = (const float*)d_in[2];
  const float* adj   = (const float*)d_in[3];
  const float* lapl  = (const float*)d_in[4];
  const float* qW1 = (const float*)d_in[5],  *qb1 = (const float*)d_in[6];
  const float* qg  = (const float*)d_in[7],  *qbt = (const float*)d_in[8];
  const float* qW2 = (const float*)d_in[9],  *qb2 = (const float*)d_in[10];
  const float* dW1 = (const float*)d_in[11], *db1 = (const float*)d_in[12];
  const float* dg  = (const float*)d_in[13], *dbt = (const float*)d_in[14];
  const float* dW2 = (const float*)d_in[15], *db2 = (const float*)d_in[16];
  const float* gatW = (const float*)d_in[17];
  const float* a1   = (const float*)d_in[18];
  const float* a2   = (const float*)d_in[19];
  const float* ln_g = (const float*)d_in[20];
  const float* ln_b = (const float*)d_in[21];
  const float* poW  = (const float*)d_in[22];
  const float* pob  = (const float*)d_in[23];
  float* out = (float*)d_out;

  float* ws = (float*)d_ws;
  float* X   = ws + OFF_X;
  u16*   Xb  = (u16*)(ws + OFF_XB);
  u16*   WHb = (u16*)(ws + OFF_WHB);
  u16*   WtA = (u16*)(ws + OFF_WTA);
  u16*   WtB = (u16*)(ws + OFF_WTB);
  float* G   = ws + OFF_G;
  u16*   Gt  = (u16*)(ws + OFF_GT);
  u16*   QPb = (u16*)(ws + OFF_QPB);
  float* Hf  = ws + OFF_HF;
  u16*   Hb  = (u16*)(ws + OFF_HB);
  float* Ff  = ws + OFF_FF;
  u16*   Fb  = (u16*)(ws + OFF_FB);
  float* NEG = ws + OFF_NEG;
  float* ACC = ws + OFF_ACC;
  int*   NCNT = (int*)(ws + OFF_NCNT);
  int*   NBR  = (int*)(ws + OFF_NBR);

  hipMemsetAsync(ACC, 0, 2 * sizeof(float), stream);
  build_nbr<<<NNODE, 256, 0, stream>>>(adj, NBR, NCNT);
  cvt_dual<<<2048, 256, 0, stream>>>(nodes, X, Xb);

  // ---- GNN layers
  for (int l = 0; l < NLAY; ++l) {
    cvt_transpose<<<dim3(2, 16, 8), 256, 0, stream>>>(
        gatW + (size_t)l * NHEAD * ED * HD, WtA, ED, HD, (long)ED * HD, (long)HD * ED);
    gemm128<<<dim3(GH / 128, NNODE / 128), 256, 0, stream>>>(
        Xb, WtA, WtA, nullptr, WHb, nullptr, nullptr, NNODE, GH, ED, NNODE, 1.f);
    fused_att<<<NNODE, 256, 0, stream>>>(
        WHb, a1 + (size_t)l * NHEAD * HD, a2 + (size_t)l * NHEAD * HD,
        NBR, NCNT, X, Xb, ln_g + (size_t)l * GH, ln_b + (size_t)l * GH);
  }

  // ---- graph embeds + laplacian term
  cvt_transpose<<<dim3(16, 16, 1), 256, 0, stream>>>(poW, WtA, GH, ED, 0, 0);
  gemm128<<<dim3(ED / 128, NNODE / 128), 256, 0, stream>>>(
      Xb, WtA, WtA, G, nullptr, pob, pob, NNODE, ED, GH, NNODE, 1.f);
  cvt_transpose<<<dim3(16, 32, 1), 256, 0, stream>>>(G, Gt, NNODE, ED, 0, 0);
  lap_gemm<<<dim3(ED / 128, NNODE / 128, 2), 256, 0, stream>>>(lapl, Gt, G, ACC);

  // ---- fused q|d MLP (rows 0-1023 = query, 1024-2047 = docs)
  qd_cvt<<<2048, 256, 0, stream>>>(query, docs, QPb);
  cvt_transpose<<<dim3(16, 16, 1), 256, 0, stream>>>(qW1, WtA, ED, ED, 0, 0);
  cvt_transpose<<<dim3(16, 16, 1), 256, 0, stream>>>(dW1, WtB, ED, ED, 0, 0);
  gemm128<<<dim3(ED / 128, 2 * BQ / 128), 256, 0, stream>>>(
      QPb, WtA, WtB, Hf, nullptr, qb1, db1, 2 * BQ, ED, ED, BQ, 1.f);
  ln_gelu<<<2 * BQ, 256, 0, stream>>>(Hf, Hb, qg, qbt, dg, dbt);
  cvt_transpose<<<dim3(16, 16, 1), 256, 0, stream>>>(qW2, WtA, ED, ED, 0, 0);
  cvt_transpose<<<dim3(16, 16, 1), 256, 0, stream>>>(dW2, WtB, ED, ED, 0, 0);
  gemm128<<<dim3(ED / 128, 2 * BQ / 128), 256, 0, stream>>>(
      Hb, WtA, WtB, Ff, nullptr, qb2, db2, 2 * BQ, ED, ED, BQ, 1.f);
  l2norm_k<<<2 * BQ, 256, 0, stream>>>(Ff, Fb);

  // ---- similarities + InfoNCE
  gemm128<<<dim3(BQ / 128, BQ / 128), 256, 0, stream>>>(
      Fb, Fb + (size_t)BQ * ED, Fb + (size_t)BQ * ED, NEG, nullptr,
      nullptr, nullptr, BQ, BQ, ED, BQ, 20.f);
  lse_kernel<<<BQ, 256, 0, stream>>>(NEG, ACC);

  final_kernel<<<1, 1, 0, stream>>>(ACC, out);
}

// Round 6
// 418.449 us; speedup vs baseline: 1.6179x; 1.1884x over previous
//
#include <hip/hip_runtime.h>
#include <math.h>

// ---------------- problem constants ----------------
#define ED    1024
#define GH    1024
#define NLAY  3
#define NHEAD 8
#define HD    128
#define NNODE 2048
#define BQ    1024
#define CAP   192

typedef unsigned short u16;
typedef __attribute__((ext_vector_type(8))) short short8;
typedef __attribute__((ext_vector_type(4))) float f32x4;

// ---------------- workspace layout (float units); ~76MB of 268MB ----------
static const size_t OFF_X    = 0;         // [2048][1024] fp32
static const size_t OFF_XB   = 2097152;   // bf16 shadow
static const size_t OFF_WHB  = 3145728;   // [2048][1024] bf16 Wh
static const size_t OFF_WTG  = 4194304;   // [3][1024][1024] bf16 gatW^T
static const size_t OFF_WTPO = 5767168;   // [1024][1024] bf16
static const size_t OFF_WTQ1 = 6291456;
static const size_t OFF_WTD1 = 6815744;
static const size_t OFF_WTQ2 = 7340032;
static const size_t OFF_WTD2 = 7864320;
static const size_t OFF_G    = 8388608;   // [2048][1024] fp32
static const size_t OFF_GT   = 10485760;  // [1024][2048] bf16
static const size_t OFF_QPB  = 11534336;  // [2048][1024] bf16 q|d
static const size_t OFF_HF   = 12582912;  // [2048][1024] fp32
static const size_t OFF_HB   = 14680064;  // bf16
static const size_t OFF_FF   = 15728640;  // [2048][1024] fp32
static const size_t OFF_FB   = 17825792;  // bf16 normalized
static const size_t OFF_NEG  = 18874368;  // [1024][1024] fp32
static const size_t OFF_ACC  = 19922944;
static const size_t OFF_NCNT = 19922952;  // int*
static const size_t OFF_NBR  = 19925000;  // int*

// ---------------- helpers ----------------
__device__ __forceinline__ u16 f2bf(float f) {
  unsigned int u = __float_as_uint(f);
  return (u16)((u + 0x7fffu + ((u >> 16) & 1u)) >> 16);
}
__device__ __forceinline__ float bf2f(u16 u) {
  return __uint_as_float(((unsigned int)u) << 16);
}

__device__ __forceinline__ float waveSum(float v) {
#pragma unroll
  for (int off = 32; off; off >>= 1) v += __shfl_xor(v, off, 64);
  return v;
}
__device__ __forceinline__ float waveMax(float v) {
#pragma unroll
  for (int off = 32; off; off >>= 1) v = fmaxf(v, __shfl_xor(v, off, 64));
  return v;
}
__device__ __forceinline__ float blockSum(float v) {
  __shared__ float buf[4];
  int lane = threadIdx.x & 63, wid = threadIdx.x >> 6, nw = (blockDim.x + 63) >> 6;
  v = waveSum(v);
  __syncthreads();
  if (lane == 0) buf[wid] = v;
  __syncthreads();
  float r = buf[0];
  for (int i = 1; i < nw; ++i) r += buf[i];
  return r;
}
__device__ __forceinline__ float blockMax(float v) {
  __shared__ float buf[4];
  int lane = threadIdx.x & 63, wid = threadIdx.x >> 6, nw = (blockDim.x + 63) >> 6;
  v = waveMax(v);
  __syncthreads();
  if (lane == 0) buf[wid] = v;
  __syncthreads();
  float r = buf[0];
  for (int i = 1; i < nw; ++i) r = fmaxf(r, buf[i]);
  return r;
}

// ------------- core 128x128 bf16 MFMA GEMM (round-4 pipeline, verified) ----
// A [M,K] bf16 rm. Bt = B0 for rows<split else B1 ([N,K] bf16 rm).
__global__ __launch_bounds__(256) void gemm128(
    const u16* __restrict__ A, const u16* __restrict__ B0,
    const u16* __restrict__ B1, float* __restrict__ C, u16* __restrict__ Cb,
    const float* __restrict__ bias0, const float* __restrict__ bias1,
    int M, int N, int K, int split, float scale) {
  __shared__ u16 As[2][128][32];
  __shared__ u16 Bs[2][128][32];
  const int tid = threadIdx.x, wave = tid >> 6, lane = tid & 63;
  const int bm = blockIdx.y * 128, bn = blockIdx.x * 128;
  const u16* Bt = (bm < split) ? B0 : B1;
  const float* bias = (bm < split) ? bias0 : bias1;

  const int sr = tid >> 2, ss = tid & 3;
  const u16* ga0 = A  + (size_t)(bm + sr) * K + ss * 8;
  const u16* ga1 = A  + (size_t)(bm + sr + 64) * K + ss * 8;
  const u16* gb0 = Bt + (size_t)(bn + sr) * K + ss * 8;
  const u16* gb1 = Bt + (size_t)(bn + sr + 64) * K + ss * 8;

  const int r16 = lane & 15, kg = lane >> 4;
  const int wm = (wave >> 1) * 64, wn = (wave & 1) * 64;

  f32x4 acc[4][4] = {};
  const int nk = K >> 5;

  float4 pa0 = *(const float4*)ga0;
  float4 pa1 = *(const float4*)ga1;
  float4 pb0 = *(const float4*)gb0;
  float4 pb1 = *(const float4*)gb1;

  for (int kt = 0; kt < nk; ++kt) {
    const int p = kt & 1;
    *(float4*)&As[p][sr][ss * 8]      = pa0;
    *(float4*)&As[p][sr + 64][ss * 8] = pa1;
    *(float4*)&Bs[p][sr][ss * 8]      = pb0;
    *(float4*)&Bs[p][sr + 64][ss * 8] = pb1;
    __syncthreads();
    if (kt + 1 < nk) {
      ga0 += 32; ga1 += 32; gb0 += 32; gb1 += 32;
      pa0 = *(const float4*)ga0;
      pa1 = *(const float4*)ga1;
      pb0 = *(const float4*)gb0;
      pb1 = *(const float4*)gb1;
    }
    short8 av[4], bv[4];
#pragma unroll
    for (int i = 0; i < 4; ++i)
      av[i] = *(const short8*)&As[p][wm + i * 16 + r16][kg * 8];
#pragma unroll
    for (int j = 0; j < 4; ++j)
      bv[j] = *(const short8*)&Bs[p][wn + j * 16 + r16][kg * 8];
#pragma unroll
    for (int i = 0; i < 4; ++i)
#pragma unroll
      for (int j = 0; j < 4; ++j)
        acc[i][j] = __builtin_amdgcn_mfma_f32_16x16x32_bf16(av[i], bv[j], acc[i][j], 0, 0, 0);
  }

  if (C) {
#pragma unroll
    for (int j = 0; j < 4; ++j) {
      int col = bn + wn + j * 16 + r16;
      float bvv = bias ? bias[col] : 0.f;
#pragma unroll
      for (int i = 0; i < 4; ++i) {
        int row0 = bm + wm + i * 16 + kg * 4;
        float* cp = C + (size_t)row0 * N + col;
#pragma unroll
        for (int r = 0; r < 4; ++r)
          cp[(size_t)r * N] = acc[i][j][r] * scale + bvv;
      }
    }
  }
  if (Cb) {
#pragma unroll
    for (int j = 0; j < 4; ++j) {
      int col = bn + wn + j * 16 + r16;
      float bvv = bias ? bias[col] : 0.f;
#pragma unroll
      for (int i = 0; i < 4; ++i) {
        int row0 = bm + wm + i * 16 + kg * 4;
        u16* cp = Cb + (size_t)row0 * N + col;
#pragma unroll
        for (int r = 0; r < 4; ++r)
          cp[(size_t)r * N] = f2bf(acc[i][j][r] * scale + bvv);
      }
    }
  }
}

// ------------- dual-problem GEMM: two independent N=K=1024 GEMMs in one
// launch (blockIdx.z selects). Fills the machine when each alone is 128 blks.
__global__ __launch_bounds__(256) void gemm_dual(
    const u16* __restrict__ A0, const u16* __restrict__ B00,
    const u16* __restrict__ B01, float* __restrict__ C0, u16* __restrict__ D0,
    const float* __restrict__ e0, const float* __restrict__ f0, int M0, int sp0, float sc0,
    const u16* __restrict__ A1, const u16* __restrict__ B10,
    const u16* __restrict__ B11, float* __restrict__ C1, u16* __restrict__ D1,
    const float* __restrict__ e1, const float* __restrict__ f1, int M1, int sp1, float sc1) {
  const int z = blockIdx.z;
  const u16* A   = z ? A1 : A0;
  const u16* Bt0 = z ? B10 : B00;
  const u16* Bt1 = z ? B11 : B01;
  float* C = z ? C1 : C0;
  u16*   D = z ? D1 : D0;
  const float* bias0 = z ? e1 : e0;
  const float* bias1 = z ? f1 : f0;
  const int M = z ? M1 : M0, split = z ? sp1 : sp0;
  const float scale = z ? sc1 : sc0;
  const int bm = blockIdx.y * 128, bn = blockIdx.x * 128;
  if (bm >= M) return;
  const int N = 1024, K = 1024;
  const u16* Bt = (bm < split) ? Bt0 : Bt1;
  const float* bias = (bm < split) ? bias0 : bias1;

  __shared__ u16 As[2][128][32];
  __shared__ u16 Bs[2][128][32];
  const int tid = threadIdx.x, wave = tid >> 6, lane = tid & 63;
  const int sr = tid >> 2, ss = tid & 3;
  const u16* ga0 = A  + (size_t)(bm + sr) * K + ss * 8;
  const u16* ga1 = A  + (size_t)(bm + sr + 64) * K + ss * 8;
  const u16* gb0 = Bt + (size_t)(bn + sr) * K + ss * 8;
  const u16* gb1 = Bt + (size_t)(bn + sr + 64) * K + ss * 8;
  const int r16 = lane & 15, kg = lane >> 4;
  const int wm = (wave >> 1) * 64, wn = (wave & 1) * 64;

  f32x4 acc[4][4] = {};
  const int nk = 32;

  float4 pa0 = *(const float4*)ga0;
  float4 pa1 = *(const float4*)ga1;
  float4 pb0 = *(const float4*)gb0;
  float4 pb1 = *(const float4*)gb1;

  for (int kt = 0; kt < nk; ++kt) {
    const int p = kt & 1;
    *(float4*)&As[p][sr][ss * 8]      = pa0;
    *(float4*)&As[p][sr + 64][ss * 8] = pa1;
    *(float4*)&Bs[p][sr][ss * 8]      = pb0;
    *(float4*)&Bs[p][sr + 64][ss * 8] = pb1;
    __syncthreads();
    if (kt + 1 < nk) {
      ga0 += 32; ga1 += 32; gb0 += 32; gb1 += 32;
      pa0 = *(const float4*)ga0;
      pa1 = *(const float4*)ga1;
      pb0 = *(const float4*)gb0;
      pb1 = *(const float4*)gb1;
    }
    short8 av[4], bv[4];
#pragma unroll
    for (int i = 0; i < 4; ++i)
      av[i] = *(const short8*)&As[p][wm + i * 16 + r16][kg * 8];
#pragma unroll
    for (int j = 0; j < 4; ++j)
      bv[j] = *(const short8*)&Bs[p][wn + j * 16 + r16][kg * 8];
#pragma unroll
    for (int i = 0; i < 4; ++i)
#pragma unroll
      for (int j = 0; j < 4; ++j)
        acc[i][j] = __builtin_amdgcn_mfma_f32_16x16x32_bf16(av[i], bv[j], acc[i][j], 0, 0, 0);
  }

  if (C) {
#pragma unroll
    for (int j = 0; j < 4; ++j) {
      int col = bn + wn + j * 16 + r16;
      float bvv = bias ? bias[col] : 0.f;
#pragma unroll
      for (int i = 0; i < 4; ++i) {
        int row0 = bm + wm + i * 16 + kg * 4;
        float* cp = C + (size_t)row0 * N + col;
#pragma unroll
        for (int r = 0; r < 4; ++r)
          cp[(size_t)r * N] = acc[i][j][r] * scale + bvv;
      }
    }
  }
  if (D) {
#pragma unroll
    for (int j = 0; j < 4; ++j) {
      int col = bn + wn + j * 16 + r16;
      float bvv = bias ? bias[col] : 0.f;
#pragma unroll
      for (int i = 0; i < 4; ++i) {
        int row0 = bm + wm + i * 16 + kg * 4;
        u16* cp = D + (size_t)row0 * N + col;
#pragma unroll
        for (int r = 0; r < 4; ++r)
          cp[(size_t)r * N] = f2bf(acc[i][j][r] * scale + bvv);
      }
    }
  }
}

// ------------- lap GEMM v2: split-K=4, XCD-locality swizzle, fused dot -----
// 512 linear blocks: member = n>>6 (bn, 8), group = n&63 -> (by 16, bz 4).
// All 8 members of a group share n%8 -> same XCD -> A strip fetched once/L2.
__global__ __launch_bounds__(256) void lap_gemm(
    const float* __restrict__ A, const u16* __restrict__ Bt,
    const float* __restrict__ G, float* __restrict__ acc_out) {
  __shared__ u16 As[2][128][32];
  __shared__ u16 Bs[2][128][32];
  const int tid = threadIdx.x, wave = tid >> 6, lane = tid & 63;
  const int n = blockIdx.x;
  const int member = n >> 6, gzy = n & 63;
  const int bm = (gzy & 15) * 128, bn = member * 128, k0 = (gzy >> 4) * 512;

  const int sr = tid >> 2, ss = tid & 3;
  const float* gA0 = A + (size_t)(bm + sr) * NNODE + k0 + ss * 8;
  const float* gA1 = gA0 + (size_t)64 * NNODE;
  const u16* gb0 = Bt + (size_t)(bn + sr) * NNODE + k0 + ss * 8;
  const u16* gb1 = Bt + (size_t)(bn + sr + 64) * NNODE + k0 + ss * 8;

  const int r16 = lane & 15, kg = lane >> 4;
  const int wm = (wave >> 1) * 64, wn = (wave & 1) * 64;

  f32x4 acc[4][4] = {};
  const int nk = 16;   // 512 / 32

  float4 a0l = *(const float4*)gA0, a0h = *(const float4*)(gA0 + 4);
  float4 a1l = *(const float4*)gA1, a1h = *(const float4*)(gA1 + 4);
  float4 pb0 = *(const float4*)gb0;
  float4 pb1 = *(const float4*)gb1;

  for (int kt = 0; kt < nk; ++kt) {
    const int p = kt & 1;
    {
      ushort4 lo, hi;
      lo.x = f2bf(a0l.x); lo.y = f2bf(a0l.y); lo.z = f2bf(a0l.z); lo.w = f2bf(a0l.w);
      hi.x = f2bf(a0h.x); hi.y = f2bf(a0h.y); hi.z = f2bf(a0h.z); hi.w = f2bf(a0h.w);
      *(ushort4*)&As[p][sr][ss * 8]     = lo;
      *(ushort4*)&As[p][sr][ss * 8 + 4] = hi;
      lo.x = f2bf(a1l.x); lo.y = f2bf(a1l.y); lo.z = f2bf(a1l.z); lo.w = f2bf(a1l.w);
      hi.x = f2bf(a1h.x); hi.y = f2bf(a1h.y); hi.z = f2bf(a1h.z); hi.w = f2bf(a1h.w);
      *(ushort4*)&As[p][sr + 64][ss * 8]     = lo;
      *(ushort4*)&As[p][sr + 64][ss * 8 + 4] = hi;
    }
    *(float4*)&Bs[p][sr][ss * 8]      = pb0;
    *(float4*)&Bs[p][sr + 64][ss * 8] = pb1;
    __syncthreads();
    if (kt + 1 < nk) {
      gA0 += 32; gA1 += 32; gb0 += 32; gb1 += 32;
      a0l = *(const float4*)gA0; a0h = *(const float4*)(gA0 + 4);
      a1l = *(const float4*)gA1; a1h = *(const float4*)(gA1 + 4);
      pb0 = *(const float4*)gb0;
      pb1 = *(const float4*)gb1;
    }
    short8 av[4], bv[4];
#pragma unroll
    for (int i = 0; i < 4; ++i)
      av[i] = *(const short8*)&As[p][wm + i * 16 + r16][kg * 8];
#pragma unroll
    for (int j = 0; j < 4; ++j)
      bv[j] = *(const short8*)&Bs[p][wn + j * 16 + r16][kg * 8];
#pragma unroll
    for (int i = 0; i < 4; ++i)
#pragma unroll
      for (int j = 0; j < 4; ++j)
        acc[i][j] = __builtin_amdgcn_mfma_f32_16x16x32_bf16(av[i], bv[j], acc[i][j], 0, 0, 0);
  }

  float sum = 0.f;
#pragma unroll
  for (int j = 0; j < 4; ++j) {
    int col = bn + wn + j * 16 + r16;
#pragma unroll
    for (int i = 0; i < 4; ++i) {
      int row0 = bm + wm + i * 16 + kg * 4;
      const float* gp = G + (size_t)row0 * ED + col;
#pragma unroll
      for (int r = 0; r < 4; ++r)
        sum += acc[i][j][r] * gp[(size_t)r * ED];
    }
  }
  sum = blockSum(sum);
  if (tid == 0) atomicAdd(acc_out, sum);
}

// ------------- fused GAT attention + LN + elu + residual (pairwise ILP) ----
__global__ __launch_bounds__(256) void fused_att(
    const u16* __restrict__ WHb, const float* __restrict__ a1l,
    const float* __restrict__ a2l, const int* __restrict__ nbr,
    const int* __restrict__ ncnt, float* __restrict__ X, u16* __restrict__ Xb,
    const float* __restrict__ g, const float* __restrict__ b) {
  __shared__ int snb[CAP];
  const int n = blockIdx.x, t = threadIdx.x;
  const int cnt = ncnt[n];
  for (int j = t; j < cnt; j += 256) snb[j] = nbr[n * CAP + j];

  const float4 a1v = *(const float4*)(a1l + (t << 2));
  const float4 a2v = *(const float4*)(a2l + (t << 2));

  ushort4 w0 = *(const ushort4*)(WHb + ((size_t)n << 10) + (t << 2));
  float s1 = bf2f(w0.x) * a1v.x + bf2f(w0.y) * a1v.y +
             bf2f(w0.z) * a1v.z + bf2f(w0.w) * a1v.w;
#pragma unroll
  for (int off = 16; off; off >>= 1) s1 += __shfl_xor(s1, off, 64);

  __syncthreads();

  float mh = -1e30f, lh = 0.f;
  float ac0 = 0.f, ac1 = 0.f, ac2 = 0.f, ac3 = 0.f;
  ushort4 wx0 = *(const ushort4*)(WHb + ((size_t)snb[0] << 10) + (t << 2));
  ushort4 wx1 = wx0;
  if (cnt > 1) wx1 = *(const ushort4*)(WHb + ((size_t)snb[1] << 10) + (t << 2));
  int j = 0;
  for (; j + 1 < cnt; j += 2) {
    float va0 = bf2f(wx0.x), va1 = bf2f(wx0.y), va2 = bf2f(wx0.z), va3 = bf2f(wx0.w);
    float vb0 = bf2f(wx1.x), vb1 = bf2f(wx1.y), vb2 = bf2f(wx1.z), vb3 = bf2f(wx1.w);
    int j2 = (j + 2 < cnt) ? j + 2 : 0;
    int j3 = (j + 3 < cnt) ? j + 3 : 0;
    wx0 = *(const ushort4*)(WHb + ((size_t)snb[j2] << 10) + (t << 2));
    wx1 = *(const ushort4*)(WHb + ((size_t)snb[j3] << 10) + (t << 2));
    float s2a = va0 * a2v.x + va1 * a2v.y + va2 * a2v.z + va3 * a2v.w;
    float s2b = vb0 * a2v.x + vb1 * a2v.y + vb2 * a2v.z + vb3 * a2v.w;
#pragma unroll
    for (int off = 16; off; off >>= 1) {
      s2a += __shfl_xor(s2a, off, 64);
      s2b += __shfl_xor(s2b, off, 64);
    }
    float ea = s1 + s2a; ea = ea > 0.f ? ea : 0.2f * ea;
    float eb = s1 + s2b; eb = eb > 0.f ? eb : 0.2f * eb;
    float nm = fmaxf(mh, fmaxf(ea, eb));
    float al = __expf(mh - nm);
    float pa = __expf(ea - nm);
    float pb = __expf(eb - nm);
    lh = lh * al + pa + pb;
    ac0 = ac0 * al + pa * va0 + pb * vb0;
    ac1 = ac1 * al + pa * va1 + pb * vb1;
    ac2 = ac2 * al + pa * va2 + pb * vb2;
    ac3 = ac3 * al + pa * va3 + pb * vb3;
    mh = nm;
  }
  if (j < cnt) {
    float va0 = bf2f(wx0.x), va1 = bf2f(wx0.y), va2 = bf2f(wx0.z), va3 = bf2f(wx0.w);
    float s2 = va0 * a2v.x + va1 * a2v.y + va2 * a2v.z + va3 * a2v.w;
#pragma unroll
    for (int off = 16; off; off >>= 1) s2 += __shfl_xor(s2, off, 64);
    float e = s1 + s2; e = e > 0.f ? e : 0.2f * e;
    float nm = fmaxf(mh, e);
    float al = __expf(mh - nm), p = __expf(e - nm);
    lh = lh * al + p;
    ac0 = ac0 * al + p * va0;
    ac1 = ac1 * al + p * va1;
    ac2 = ac2 * al + p * va2;
    ac3 = ac3 * al + p * va3;
    mh = nm;
  }
  float inv = 1.f / lh;
  float o0 = ac0 * inv, o1 = ac1 * inv, o2 = ac2 * inv, o3 = ac3 * inv;

  float s  = o0 + o1 + o2 + o3;
  float sq = o0 * o0 + o1 * o1 + o2 * o2 + o3 * o3;
  float mean = blockSum(s) * (1.f / 1024.f);
  float var  = blockSum(sq) * (1.f / 1024.f) - mean * mean;
  float rstd = rsqrtf(fmaxf(var, 0.f) + 1e-5f);
  float4 xv = *(float4*)&X[((size_t)n << 10) + (t << 2)];
  float ov[4] = {o0, o1, o2, o3};
  float xa[4] = {xv.x, xv.y, xv.z, xv.w};
#pragma unroll
  for (int i = 0; i < 4; ++i) {
    int c = (t << 2) + i;
    float y = (ov[i] - mean) * rstd * g[c] + b[c];
    y = y > 0.f ? y : expm1f(y);
    xa[i] += y;
  }
  *(float4*)&X[((size_t)n << 10) + (t << 2)] = make_float4(xa[0], xa[1], xa[2], xa[3]);
  ushort4 o;
  o.x = f2bf(xa[0]); o.y = f2bf(xa[1]); o.z = f2bf(xa[2]); o.w = f2bf(xa[3]);
  *(ushort4*)&Xb[((size_t)n << 10) + (t << 2)] = o;
}

// ---------------- small kernels ----------------
__global__ void build_nbr(const float* __restrict__ adj, int* __restrict__ nbr,
                          int* __restrict__ ncnt, float* __restrict__ acc) {
  __shared__ int cnt;
  int n = blockIdx.x, tid = threadIdx.x;
  if (n == 0 && tid < 2) acc[tid] = 0.f;
  if (tid == 0) cnt = 0;
  __syncthreads();
  for (int c = tid; c < NNODE; c += 256) {
    if (adj[((size_t)n << 11) + c] > 0.f) {
      int p = atomicAdd(&cnt, 1);
      if (p < CAP) nbr[n * CAP + p] = c;
    }
  }
  __syncthreads();
  if (tid == 0) ncnt[n] = cnt < CAP ? cnt : CAP;
}

__global__ __launch_bounds__(256) void cvt_dual(const float* __restrict__ in,
                                                float* __restrict__ Xf,
                                                u16* __restrict__ Xb) {
  int i = blockIdx.x * 256 + threadIdx.x;
  float4 v = ((const float4*)in)[i];
  ((float4*)Xf)[i] = v;
  ushort4 o;
  o.x = f2bf(v.x); o.y = f2bf(v.y); o.z = f2bf(v.z); o.w = f2bf(v.w);
  ((ushort4*)Xb)[i] = o;
}

__global__ __launch_bounds__(256) void qd_cvt(const float* __restrict__ q,
                                              const float* __restrict__ d,
                                              u16* __restrict__ out) {
  int i = blockIdx.x * 256 + threadIdx.x;
  const int half = BQ * ED / 4;
  const float* src = (i < half) ? q : d;
  int j = (i < half) ? i : i - half;
  float4 v = ((const float4*)src)[j];
  ushort4 o;
  o.x = f2bf(v.x); o.y = f2bf(v.y); o.z = f2bf(v.z); o.w = f2bf(v.w);
  ((ushort4*)out)[i] = o;
}

// in fp32 [R][C] (batch stride inb) -> out bf16 [C][R] (batch stride outb)
__global__ __launch_bounds__(256) void cvt_transpose(
    const float* __restrict__ in, u16* __restrict__ out,
    int R, int C, long inb, long outb) {
  __shared__ float T[64][65];
  const float* ip = in + (size_t)blockIdx.z * inb;
  u16* op = out + (size_t)blockIdx.z * outb;
  int r0 = blockIdx.y * 64, c0 = blockIdx.x * 64;
  int t = threadIdx.x;
#pragma unroll
  for (int p = 0; p < 4; ++p) {
    int row = p * 16 + (t >> 4), col = (t & 15) * 4;
    float4 v = *(const float4*)&ip[(size_t)(r0 + row) * C + c0 + col];
    T[row][col] = v.x; T[row][col + 1] = v.y;
    T[row][col + 2] = v.z; T[row][col + 3] = v.w;
  }
  __syncthreads();
#pragma unroll
  for (int p = 0; p < 4; ++p) {
    int c = p * 16 + (t >> 4), r = (t & 15) * 4;
    ushort4 o;
    o.x = f2bf(T[r][c]); o.y = f2bf(T[r + 1][c]);
    o.z = f2bf(T[r + 2][c]); o.w = f2bf(T[r + 3][c]);
    *(ushort4*)&op[(size_t)(c0 + c) * R + r0 + r] = o;
  }
}

__global__ __launch_bounds__(256) void ln_gelu(
    const float* __restrict__ IN, u16* __restrict__ OUT,
    const float* __restrict__ g0, const float* __restrict__ b0,
    const float* __restrict__ g1, const float* __restrict__ b1) {
  int row = blockIdx.x, tid = threadIdx.x;
  const float* g = (row < 1024) ? g0 : g1;
  const float* b = (row < 1024) ? b0 : b1;
  float4 v = *(const float4*)&IN[((size_t)row << 10) + (tid << 2)];
  float s = v.x + v.y + v.z + v.w;
  float sq = v.x * v.x + v.y * v.y + v.z * v.z + v.w * v.w;
  float mean = blockSum(s) * (1.f / 1024.f);
  float var = blockSum(sq) * (1.f / 1024.f) - mean * mean;
  float rstd = rsqrtf(fmaxf(var, 0.f) + 1e-5f);
  float vals[4] = {v.x, v.y, v.z, v.w};
  ushort4 o;
  u16* oa = (u16*)&o;
#pragma unroll
  for (int i = 0; i < 4; ++i) {
    int c = (tid << 2) + i;
    float y = (vals[i] - mean) * rstd * g[c] + b[c];
    y = 0.5f * y * (1.f + erff(y * 0.70710678118654752f));
    oa[i] = f2bf(y);
  }
  *(ushort4*)&OUT[((size_t)row << 10) + (tid << 2)] = o;
}

__global__ __launch_bounds__(256) void l2norm_k(const float* __restrict__ IN,
                                                u16* __restrict__ OUT) {
  int row = blockIdx.x, tid = threadIdx.x;
  float4 v = *(const float4*)&IN[((size_t)row << 10) + (tid << 2)];
  float sq = v.x * v.x + v.y * v.y + v.z * v.z + v.w * v.w;
  float s = blockSum(sq);
  float inv = 1.f / fmaxf(sqrtf(s), 1e-12f);
  ushort4 o;
  o.x = f2bf(v.x * inv); o.y = f2bf(v.y * inv);
  o.z = f2bf(v.z * inv); o.w = f2bf(v.w * inv);
  *(ushort4*)&OUT[((size_t)row << 10) + (tid << 2)] = o;
}

__global__ __launch_bounds__(256) void lse_kernel(const float* __restrict__ NEG,
                                                  float* __restrict__ acc) {
  int bq = blockIdx.x, tid = threadIdx.x;
  const float* row = NEG + ((size_t)bq << 10);
  float4 v = *(const float4*)&row[tid << 2];
  float lm = fmaxf(fmaxf(v.x, v.y), fmaxf(v.z, v.w));
  float m = blockMax(lm);
  float ls = __expf(v.x - m) + __expf(v.y - m) + __expf(v.z - m) + __expf(v.w - m);
  float ssum = blockSum(ls);
  if (tid == 0) {
    float pos = row[bq];
    float loss = m + logf(ssum + __expf(pos - m)) - pos;
    atomicAdd(acc + 1, loss);
  }
}

__global__ void final_kernel(const float* __restrict__ acc, float* __restrict__ out) {
  float lap = acc[0] / 2048.f;
  float info = acc[1] / 1024.f;
  out[0] = info + 0.1f * lap;
  out[1] = info;
  out[2] = lap;
}

// ---------------- host launcher ----------------
extern "C" void kernel_launch(void* const* d_in, const int* in_sizes, int n_in,
                              void* d_out, int out_size, void* d_ws, size_t ws_size,
                              hipStream_t stream) {
  const float* query = (const float*)d_in[0];
  const float* docs  = (const float*)d_in[1];
  const float* nodes = (const float*)d_in[2];
  const float* adj   = (const float*)d_in[3];
  const float* lapl  = (const float*)d_in[4];
  const float* qW1 = (const float*)d_in[5],  *qb1 = (const float*)d_in[6];
  const float* qg  = (const float*)d_in[7],  *qbt = (const float*)d_in[8];
  const float* qW2 = (const float*)d_in[9],  *qb2 = (const float*)d_in[10];
  const float* dW1 = (const float*)d_in[11], *db1 = (const float*)d_in[12];
  const float* dg  = (const float*)d_in[13], *dbt = (const float*)d_in[14];
  const float* dW2 = (const float*)d_in[15], *db2 = (const float*)d_in[16];
  const float* gatW = (const float*)d_in[17];
  const float* a1   = (const float*)d_in[18];
  const float* a2   = (const float*)d_in[19];
  const float* ln_g = (const float*)d_in[20];
  const float* ln_b = (const float*)d_in[21];
  const float* poW  = (const float*)d_in[22];
  const float* pob  = (const float*)d_in[23];
  float* out = (float*)d_out;

  float* ws = (float*)d_ws;
  float* X    = ws + OFF_X;
  u16*   Xb   = (u16*)(ws + OFF_XB);
  u16*   WHb  = (u16*)(ws + OFF_WHB);
  u16*   WtG  = (u16*)(ws + OFF_WTG);
  u16*   WtPO = (u16*)(ws + OFF_WTPO);
  u16*   WtQ1 = (u16*)(ws + OFF_WTQ1);
  u16*   WtD1 = (u16*)(ws + OFF_WTD1);
  u16*   WtQ2 = (u16*)(ws + OFF_WTQ2);
  u16*   WtD2 = (u16*)(ws + OFF_WTD2);
  float* G    = ws + OFF_G;
  u16*   Gt   = (u16*)(ws + OFF_GT);
  u16*   QPb  = (u16*)(ws + OFF_QPB);
  float* Hf   = ws + OFF_HF;
  u16*   Hb   = (u16*)(ws + OFF_HB);
  float* Ff   = ws + OFF_FF;
  u16*   Fb   = (u16*)(ws + OFF_FB);
  float* NEG  = ws + OFF_NEG;
  float* ACC  = ws + OFF_ACC;
  int*   NCNT = (int*)(ws + OFF_NCNT);
  int*   NBR  = (int*)(ws + OFF_NBR);

  const size_t WSL = (size_t)GH * ED;   // per-layer gatW^T stride

  // ---- prep (all independent)
  build_nbr<<<NNODE, 256, 0, stream>>>(adj, NBR, NCNT, ACC);
  cvt_dual<<<2048, 256, 0, stream>>>(nodes, X, Xb);
  qd_cvt<<<2048, 256, 0, stream>>>(query, docs, QPb);
  cvt_transpose<<<dim3(2, 16, 24), 256, 0, stream>>>(
      gatW, WtG, ED, HD, (long)ED * HD, (long)HD * ED);
  cvt_transpose<<<dim3(16, 16, 1), 256, 0, stream>>>(poW, WtPO, GH, ED, 0, 0);
  cvt_transpose<<<dim3(16, 16, 1), 256, 0, stream>>>(qW1, WtQ1, ED, ED, 0, 0);
  cvt_transpose<<<dim3(16, 16, 1), 256, 0, stream>>>(dW1, WtD1, ED, ED, 0, 0);
  cvt_transpose<<<dim3(16, 16, 1), 256, 0, stream>>>(qW2, WtQ2, ED, ED, 0, 0);
  cvt_transpose<<<dim3(16, 16, 1), 256, 0, stream>>>(dW2, WtD2, ED, ED, 0, 0);

  // ---- layer 0 GAT gemm + MLP1 (batched)
  gemm_dual<<<dim3(8, 16, 2), 256, 0, stream>>>(
      Xb, WtG, WtG, nullptr, WHb, nullptr, nullptr, NNODE, NNODE, 1.f,
      QPb, WtQ1, WtD1, Hf, nullptr, qb1, db1, 2 * BQ, BQ, 1.f);
  fused_att<<<NNODE, 256, 0, stream>>>(WHb, a1, a2, NBR, NCNT, X, Xb, ln_g, ln_b);
  ln_gelu<<<2 * BQ, 256, 0, stream>>>(Hf, Hb, qg, qbt, dg, dbt);

  // ---- layer 1 GAT gemm + MLP2 (batched)
  gemm_dual<<<dim3(8, 16, 2), 256, 0, stream>>>(
      Xb, WtG + WSL, WtG + WSL, nullptr, WHb, nullptr, nullptr, NNODE, NNODE, 1.f,
      Hb, WtQ2, WtD2, Ff, nullptr, qb2, db2, 2 * BQ, BQ, 1.f);
  fused_att<<<NNODE, 256, 0, stream>>>(WHb, a1 + NHEAD * HD, a2 + NHEAD * HD,
      NBR, NCNT, X, Xb, ln_g + GH, ln_b + GH);
  l2norm_k<<<2 * BQ, 256, 0, stream>>>(Ff, Fb);

  // ---- layer 2 GAT gemm + NEG similarity (batched)
  gemm_dual<<<dim3(8, 16, 2), 256, 0, stream>>>(
      Xb, WtG + 2 * WSL, WtG + 2 * WSL, nullptr, WHb, nullptr, nullptr, NNODE, NNODE, 1.f,
      Fb, Fb + (size_t)BQ * ED, Fb + (size_t)BQ * ED, NEG, nullptr,
      nullptr, nullptr, BQ, BQ, 20.f);
  fused_att<<<NNODE, 256, 0, stream>>>(WHb, a1 + 2 * NHEAD * HD, a2 + 2 * NHEAD * HD,
      NBR, NCNT, X, Xb, ln_g + 2 * GH, ln_b + 2 * GH);
  lse_kernel<<<BQ, 256, 0, stream>>>(NEG, ACC);

  // ---- graph embeds + laplacian
  gemm128<<<dim3(ED / 128, NNODE / 128), 256, 0, stream>>>(
      Xb, WtPO, WtPO, G, nullptr, pob, pob, NNODE, ED, GH, NNODE, 1.f);
  cvt_transpose<<<dim3(16, 32, 1), 256, 0, stream>>>(G, Gt, NNODE, ED, 0, 0);
  lap_gemm<<<512, 256, 0, stream>>>(lapl, Gt, G, ACC);

  final_kernel<<<1, 1, 0, stream>>>(ACC, out);
}

// Round 7
// 381.819 us; speedup vs baseline: 1.7731x; 1.0959x over previous
//
#include <hip/hip_runtime.h>
#include <math.h>

// ---------------- problem constants ----------------
#define ED    1024
#define GH    1024
#define NLAY  3
#define NHEAD 8
#define HD    128
#define NNODE 2048
#define BQ    1024
#define CAP   192

typedef unsigned short u16;
typedef __attribute__((ext_vector_type(8))) short short8;
typedef __attribute__((ext_vector_type(4))) float f32x4;

// ---------------- workspace layout (float units) ----------------
static const size_t OFF_X    = 0;         // [2048][1024] fp32
static const size_t OFF_XB   = 2097152;   // bf16 shadow
static const size_t OFF_WHB  = 3145728;   // [2048][1024] bf16 Wh
static const size_t OFF_WTG  = 4194304;   // [3][1024][1024] bf16 gatW^T
static const size_t OFF_WTPO = 5767168;   // [1024][1024] bf16
static const size_t OFF_WTQ1 = 6291456;
static const size_t OFF_WTD1 = 6815744;
static const size_t OFF_WTQ2 = 7340032;
static const size_t OFF_WTD2 = 7864320;
static const size_t OFF_G    = 8388608;   // [2048][1024] fp32
static const size_t OFF_GT   = 10485760;  // [1024][2048] bf16 (epilogue-written)
static const size_t OFF_QPB  = 11534336;  // [2048][1024] bf16 q|d
static const size_t OFF_HF   = 12582912;  // [2048][1024] fp32
static const size_t OFF_HB   = 14680064;  // bf16
static const size_t OFF_FF   = 15728640;  // [2048][1024] fp32
static const size_t OFF_FB   = 17825792;  // bf16 normalized
static const size_t OFF_NEG  = 18874368;  // [1024][1024] fp32
static const size_t OFF_SV1  = 19922944;  // [8][2048] s1
static const size_t OFF_SV2  = 19939328;  // [8][2048] s2
static const size_t OFF_ACC  = 19955712;
static const size_t OFF_NCNT = 19955720;  // int*
static const size_t OFF_NBR  = 19957768;  // int*

// ---------------- helpers ----------------
__device__ __forceinline__ u16 f2bf(float f) {
  unsigned int u = __float_as_uint(f);
  return (u16)((u + 0x7fffu + ((u >> 16) & 1u)) >> 16);
}
__device__ __forceinline__ float bf2f(u16 u) {
  return __uint_as_float(((unsigned int)u) << 16);
}

__device__ __forceinline__ float waveSum(float v) {
#pragma unroll
  for (int off = 32; off; off >>= 1) v += __shfl_xor(v, off, 64);
  return v;
}
__device__ __forceinline__ float waveMax(float v) {
#pragma unroll
  for (int off = 32; off; off >>= 1) v = fmaxf(v, __shfl_xor(v, off, 64));
  return v;
}
__device__ __forceinline__ float blockSum(float v) {
  __shared__ float buf[4];
  int lane = threadIdx.x & 63, wid = threadIdx.x >> 6, nw = (blockDim.x + 63) >> 6;
  v = waveSum(v);
  __syncthreads();
  if (lane == 0) buf[wid] = v;
  __syncthreads();
  float r = buf[0];
  for (int i = 1; i < nw; ++i) r += buf[i];
  return r;
}
__device__ __forceinline__ float blockMax(float v) {
  __shared__ float buf[4];
  int lane = threadIdx.x & 63, wid = threadIdx.x >> 6, nw = (blockDim.x + 63) >> 6;
  v = waveMax(v);
  __syncthreads();
  if (lane == 0) buf[wid] = v;
  __syncthreads();
  float r = buf[0];
  for (int i = 1; i < nw; ++i) r = fmaxf(r, buf[i]);
  return r;
}

// ------------- core 128x128 bf16 MFMA GEMM (round-4 pipeline, verified) ----
// A [M,K] bf16 rm. Bt = B0 for rows<split else B1 ([N,K] bf16 rm).
// Outputs: C fp32, Cb bf16, Ct bf16-transposed [N][M] (each nullable).
__global__ __launch_bounds__(256) void gemm128(
    const u16* __restrict__ A, const u16* __restrict__ B0,
    const u16* __restrict__ B1, float* __restrict__ C, u16* __restrict__ Cb,
    u16* __restrict__ Ct,
    const float* __restrict__ bias0, const float* __restrict__ bias1,
    int M, int N, int K, int split, float scale) {
  __shared__ u16 As[2][128][32];
  __shared__ u16 Bs[2][128][32];
  const int tid = threadIdx.x, wave = tid >> 6, lane = tid & 63;
  const int bm = blockIdx.y * 128, bn = blockIdx.x * 128;
  const u16* Bt = (bm < split) ? B0 : B1;
  const float* bias = (bm < split) ? bias0 : bias1;

  const int sr = tid >> 2, ss = tid & 3;
  const u16* ga0 = A  + (size_t)(bm + sr) * K + ss * 8;
  const u16* ga1 = A  + (size_t)(bm + sr + 64) * K + ss * 8;
  const u16* gb0 = Bt + (size_t)(bn + sr) * K + ss * 8;
  const u16* gb1 = Bt + (size_t)(bn + sr + 64) * K + ss * 8;

  const int r16 = lane & 15, kg = lane >> 4;
  const int wm = (wave >> 1) * 64, wn = (wave & 1) * 64;

  f32x4 acc[4][4] = {};
  const int nk = K >> 5;

  float4 pa0 = *(const float4*)ga0;
  float4 pa1 = *(const float4*)ga1;
  float4 pb0 = *(const float4*)gb0;
  float4 pb1 = *(const float4*)gb1;

  for (int kt = 0; kt < nk; ++kt) {
    const int p = kt & 1;
    *(float4*)&As[p][sr][ss * 8]      = pa0;
    *(float4*)&As[p][sr + 64][ss * 8] = pa1;
    *(float4*)&Bs[p][sr][ss * 8]      = pb0;
    *(float4*)&Bs[p][sr + 64][ss * 8] = pb1;
    __syncthreads();
    if (kt + 1 < nk) {
      ga0 += 32; ga1 += 32; gb0 += 32; gb1 += 32;
      pa0 = *(const float4*)ga0;
      pa1 = *(const float4*)ga1;
      pb0 = *(const float4*)gb0;
      pb1 = *(const float4*)gb1;
    }
    short8 av[4], bv[4];
#pragma unroll
    for (int i = 0; i < 4; ++i)
      av[i] = *(const short8*)&As[p][wm + i * 16 + r16][kg * 8];
#pragma unroll
    for (int j = 0; j < 4; ++j)
      bv[j] = *(const short8*)&Bs[p][wn + j * 16 + r16][kg * 8];
#pragma unroll
    for (int i = 0; i < 4; ++i)
#pragma unroll
      for (int j = 0; j < 4; ++j)
        acc[i][j] = __builtin_amdgcn_mfma_f32_16x16x32_bf16(av[i], bv[j], acc[i][j], 0, 0, 0);
  }

  // epilogue: C/D layout col=lane&15, row=(lane>>4)*4+reg (m89-verified)
  if (C) {
#pragma unroll
    for (int j = 0; j < 4; ++j) {
      int col = bn + wn + j * 16 + r16;
      float bvv = bias ? bias[col] : 0.f;
#pragma unroll
      for (int i = 0; i < 4; ++i) {
        int row0 = bm + wm + i * 16 + kg * 4;
        float* cp = C + (size_t)row0 * N + col;
#pragma unroll
        for (int r = 0; r < 4; ++r)
          cp[(size_t)r * N] = acc[i][j][r] * scale + bvv;
      }
    }
  }
  if (Cb) {
#pragma unroll
    for (int j = 0; j < 4; ++j) {
      int col = bn + wn + j * 16 + r16;
      float bvv = bias ? bias[col] : 0.f;
#pragma unroll
      for (int i = 0; i < 4; ++i) {
        int row0 = bm + wm + i * 16 + kg * 4;
        u16* cp = Cb + (size_t)row0 * N + col;
#pragma unroll
        for (int r = 0; r < 4; ++r)
          cp[(size_t)r * N] = f2bf(acc[i][j][r] * scale + bvv);
      }
    }
  }
  if (Ct) {   // transposed bf16: Ct[col][row], contiguous in row (4 per lane)
#pragma unroll
    for (int j = 0; j < 4; ++j) {
      int col = bn + wn + j * 16 + r16;
      float bvv = bias ? bias[col] : 0.f;
#pragma unroll
      for (int i = 0; i < 4; ++i) {
        int row0 = bm + wm + i * 16 + kg * 4;
        ushort4 o;
        o.x = f2bf(acc[i][j][0] * scale + bvv);
        o.y = f2bf(acc[i][j][1] * scale + bvv);
        o.z = f2bf(acc[i][j][2] * scale + bvv);
        o.w = f2bf(acc[i][j][3] * scale + bvv);
        *(ushort4*)&Ct[(size_t)col * M + row0] = o;
      }
    }
  }
}

// ------------- dual-problem GEMM (z selects); problem 0 may emit s1/s2 -----
// Problem 0 (GAT): N-tile == one head; epilogue reduces acc·a1, acc·a2 per row.
__global__ __launch_bounds__(256) void gemm_dual(
    const u16* __restrict__ A0, const u16* __restrict__ B00,
    const u16* __restrict__ B01, float* __restrict__ C0, u16* __restrict__ D0,
    const float* __restrict__ e0, const float* __restrict__ f0, int M0, int sp0, float sc0,
    const float* __restrict__ A1v, const float* __restrict__ A2v,
    float* __restrict__ S1o, float* __restrict__ S2o,
    const u16* __restrict__ A1, const u16* __restrict__ B10,
    const u16* __restrict__ B11, float* __restrict__ C1, u16* __restrict__ D1,
    const float* __restrict__ e1, const float* __restrict__ f1, int M1, int sp1, float sc1) {
  const int z = blockIdx.z;
  const u16* A   = z ? A1 : A0;
  const u16* Bt0 = z ? B10 : B00;
  const u16* Bt1 = z ? B11 : B01;
  float* C = z ? C1 : C0;
  u16*   D = z ? D1 : D0;
  const float* bias0 = z ? e1 : e0;
  const float* bias1 = z ? f1 : f0;
  const int M = z ? M1 : M0, split = z ? sp1 : sp0;
  const float scale = z ? sc1 : sc0;
  const int bm = blockIdx.y * 128, bn = blockIdx.x * 128;
  if (bm >= M) return;
  const int N = 1024, K = 1024;
  const u16* Bt = (bm < split) ? Bt0 : Bt1;
  const float* bias = (bm < split) ? bias0 : bias1;

  __shared__ u16 As[2][128][32];
  __shared__ u16 Bs[2][128][32];
  const int tid = threadIdx.x, wave = tid >> 6, lane = tid & 63;
  const int sr = tid >> 2, ss = tid & 3;
  const u16* ga0 = A  + (size_t)(bm + sr) * K + ss * 8;
  const u16* ga1 = A  + (size_t)(bm + sr + 64) * K + ss * 8;
  const u16* gb0 = Bt + (size_t)(bn + sr) * K + ss * 8;
  const u16* gb1 = Bt + (size_t)(bn + sr + 64) * K + ss * 8;
  const int r16 = lane & 15, kg = lane >> 4;
  const int wm = (wave >> 1) * 64, wn = (wave & 1) * 64;

  f32x4 acc[4][4] = {};
  const int nk = 32;

  float4 pa0 = *(const float4*)ga0;
  float4 pa1 = *(const float4*)ga1;
  float4 pb0 = *(const float4*)gb0;
  float4 pb1 = *(const float4*)gb1;

  for (int kt = 0; kt < nk; ++kt) {
    const int p = kt & 1;
    *(float4*)&As[p][sr][ss * 8]      = pa0;
    *(float4*)&As[p][sr + 64][ss * 8] = pa1;
    *(float4*)&Bs[p][sr][ss * 8]      = pb0;
    *(float4*)&Bs[p][sr + 64][ss * 8] = pb1;
    __syncthreads();
    if (kt + 1 < nk) {
      ga0 += 32; ga1 += 32; gb0 += 32; gb1 += 32;
      pa0 = *(const float4*)ga0;
      pa1 = *(const float4*)ga1;
      pb0 = *(const float4*)gb0;
      pb1 = *(const float4*)gb1;
    }
    short8 av[4], bv[4];
#pragma unroll
    for (int i = 0; i < 4; ++i)
      av[i] = *(const short8*)&As[p][wm + i * 16 + r16][kg * 8];
#pragma unroll
    for (int j = 0; j < 4; ++j)
      bv[j] = *(const short8*)&Bs[p][wn + j * 16 + r16][kg * 8];
#pragma unroll
    for (int i = 0; i < 4; ++i)
#pragma unroll
      for (int j = 0; j < 4; ++j)
        acc[i][j] = __builtin_amdgcn_mfma_f32_16x16x32_bf16(av[i], bv[j], acc[i][j], 0, 0, 0);
  }

  if (C) {
#pragma unroll
    for (int j = 0; j < 4; ++j) {
      int col = bn + wn + j * 16 + r16;
      float bvv = bias ? bias[col] : 0.f;
#pragma unroll
      for (int i = 0; i < 4; ++i) {
        int row0 = bm + wm + i * 16 + kg * 4;
        float* cp = C + (size_t)row0 * N + col;
#pragma unroll
        for (int r = 0; r < 4; ++r)
          cp[(size_t)r * N] = acc[i][j][r] * scale + bvv;
      }
    }
  }
  if (D) {
#pragma unroll
    for (int j = 0; j < 4; ++j) {
      int col = bn + wn + j * 16 + r16;
      float bvv = bias ? bias[col] : 0.f;
#pragma unroll
      for (int i = 0; i < 4; ++i) {
        int row0 = bm + wm + i * 16 + kg * 4;
        u16* cp = D + (size_t)row0 * N + col;
#pragma unroll
        for (int r = 0; r < 4; ++r)
          cp[(size_t)r * N] = f2bf(acc[i][j][r] * scale + bvv);
      }
    }
  }

  // ---- s1/s2 epilogue (GAT problem only): head h = blockIdx.x
  if (z == 0 && S1o) {
    float c1[4], c2[4];
#pragma unroll
    for (int j = 0; j < 4; ++j) {
      int col = bn + wn + j * 16 + r16;
      c1[j] = A1v[col]; c2[j] = A2v[col];
    }
    float r1[4][4], r2[4][4];
#pragma unroll
    for (int i = 0; i < 4; ++i)
#pragma unroll
      for (int r = 0; r < 4; ++r) {
        float v1 = 0.f, v2 = 0.f;
#pragma unroll
        for (int j = 0; j < 4; ++j) {
          v1 += acc[i][j][r] * c1[j];
          v2 += acc[i][j][r] * c2[j];
        }
#pragma unroll
        for (int off = 8; off; off >>= 1) {   // reduce over r16 (lane bits 0..3)
          v1 += __shfl_xor(v1, off, 64);
          v2 += __shfl_xor(v2, off, 64);
        }
        r1[i][r] = v1; r2[i][r] = v2;
      }
    __syncthreads();                          // all waves done with As/Bs
    float* sb1 = (float*)&As[0][0][0];        // reuse LDS: [2][128] + [2][128]
    float* sb2 = sb1 + 256;
    if (r16 == 0) {
      int half = wn >> 6;
#pragma unroll
      for (int i = 0; i < 4; ++i)
#pragma unroll
        for (int r = 0; r < 4; ++r) {
          int row = wm + i * 16 + kg * 4 + r;
          sb1[half * 128 + row] = r1[i][r];
          sb2[half * 128 + row] = r2[i][r];
        }
    }
    __syncthreads();
    if (tid < 128) {
      int h = blockIdx.x;
      S1o[(h << 11) + bm + tid] = sb1[tid] + sb1[128 + tid];
      S2o[(h << 11) + bm + tid] = sb2[tid] + sb2[128 + tid];
    }
  }
}

// ------------- lap GEMM: split-K=4, XCD swizzle, fused dot (round-6) -------
__global__ __launch_bounds__(256) void lap_gemm(
    const float* __restrict__ A, const u16* __restrict__ Bt,
    const float* __restrict__ G, float* __restrict__ acc_out) {
  __shared__ u16 As[2][128][32];
  __shared__ u16 Bs[2][128][32];
  const int tid = threadIdx.x, wave = tid >> 6, lane = tid & 63;
  const int n = blockIdx.x;
  const int member = n >> 6, gzy = n & 63;
  const int bm = (gzy & 15) * 128, bn = member * 128, k0 = (gzy >> 4) * 512;

  const int sr = tid >> 2, ss = tid & 3;
  const float* gA0 = A + (size_t)(bm + sr) * NNODE + k0 + ss * 8;
  const float* gA1 = gA0 + (size_t)64 * NNODE;
  const u16* gb0 = Bt + (size_t)(bn + sr) * NNODE + k0 + ss * 8;
  const u16* gb1 = Bt + (size_t)(bn + sr + 64) * NNODE + k0 + ss * 8;

  const int r16 = lane & 15, kg = lane >> 4;
  const int wm = (wave >> 1) * 64, wn = (wave & 1) * 64;

  f32x4 acc[4][4] = {};
  const int nk = 16;

  float4 a0l = *(const float4*)gA0, a0h = *(const float4*)(gA0 + 4);
  float4 a1l = *(const float4*)gA1, a1h = *(const float4*)(gA1 + 4);
  float4 pb0 = *(const float4*)gb0;
  float4 pb1 = *(const float4*)gb1;

  for (int kt = 0; kt < nk; ++kt) {
    const int p = kt & 1;
    {
      ushort4 lo, hi;
      lo.x = f2bf(a0l.x); lo.y = f2bf(a0l.y); lo.z = f2bf(a0l.z); lo.w = f2bf(a0l.w);
      hi.x = f2bf(a0h.x); hi.y = f2bf(a0h.y); hi.z = f2bf(a0h.z); hi.w = f2bf(a0h.w);
      *(ushort4*)&As[p][sr][ss * 8]     = lo;
      *(ushort4*)&As[p][sr][ss * 8 + 4] = hi;
      lo.x = f2bf(a1l.x); lo.y = f2bf(a1l.y); lo.z = f2bf(a1l.z); lo.w = f2bf(a1l.w);
      hi.x = f2bf(a1h.x); hi.y = f2bf(a1h.y); hi.z = f2bf(a1h.z); hi.w = f2bf(a1h.w);
      *(ushort4*)&As[p][sr + 64][ss * 8]     = lo;
      *(ushort4*)&As[p][sr + 64][ss * 8 + 4] = hi;
    }
    *(float4*)&Bs[p][sr][ss * 8]      = pb0;
    *(float4*)&Bs[p][sr + 64][ss * 8] = pb1;
    __syncthreads();
    if (kt + 1 < nk) {
      gA0 += 32; gA1 += 32; gb0 += 32; gb1 += 32;
      a0l = *(const float4*)gA0; a0h = *(const float4*)(gA0 + 4);
      a1l = *(const float4*)gA1; a1h = *(const float4*)(gA1 + 4);
      pb0 = *(const float4*)gb0;
      pb1 = *(const float4*)gb1;
    }
    short8 av[4], bv[4];
#pragma unroll
    for (int i = 0; i < 4; ++i)
      av[i] = *(const short8*)&As[p][wm + i * 16 + r16][kg * 8];
#pragma unroll
    for (int j = 0; j < 4; ++j)
      bv[j] = *(const short8*)&Bs[p][wn + j * 16 + r16][kg * 8];
#pragma unroll
    for (int i = 0; i < 4; ++i)
#pragma unroll
      for (int j = 0; j < 4; ++j)
        acc[i][j] = __builtin_amdgcn_mfma_f32_16x16x32_bf16(av[i], bv[j], acc[i][j], 0, 0, 0);
  }

  float sum = 0.f;
#pragma unroll
  for (int j = 0; j < 4; ++j) {
    int col = bn + wn + j * 16 + r16;
#pragma unroll
    for (int i = 0; i < 4; ++i) {
      int row0 = bm + wm + i * 16 + kg * 4;
      const float* gp = G + (size_t)row0 * ED + col;
#pragma unroll
      for (int r = 0; r < 4; ++r)
        sum += acc[i][j][r] * gp[(size_t)r * ED];
    }
  }
  sum = blockSum(sum);
  if (tid == 0) atomicAdd(acc_out, sum);
}

// ------------- fused GAT attention v2 (parallel softmax) + LN+elu+res ------
// One block per node; 32 threads per head. Phase 1: lanes parallel over
// neighbors (s1/s2 precomputed by GEMM epilogue) -> weights in LDS.
// Phase 2: gather-FMA over neighbors (8-deep load batches).
__global__ __launch_bounds__(256) void fused_att(
    const u16* __restrict__ WHb, const float* __restrict__ S1,
    const float* __restrict__ S2, const int* __restrict__ nbr,
    const int* __restrict__ ncnt, float* __restrict__ X, u16* __restrict__ Xb,
    const float* __restrict__ g, const float* __restrict__ b) {
  __shared__ int snb[CAP];
  __shared__ float pw[NHEAD][CAP];
  const int n = blockIdx.x, t = threadIdx.x;
  const int h = t >> 5, l = t & 31;
  const int cnt = ncnt[n];
  const int cntP = (cnt + 7) & ~7;
  for (int j = t; j < cnt; j += 256) snb[j] = nbr[n * CAP + j];
  __syncthreads();
  for (int j = cnt + t; j < cntP; j += 256) snb[j] = snb[0];

  // phase 1: edge weights in parallel (lanes spread over neighbors)
  const float s1v = S1[(h << 11) + n];
  float ev[6];
  float lmax = -1e30f;
  int ne = 0;
  for (int j = l; j < cnt; j += 32) {
    float e = s1v + S2[(h << 11) + snb[j]];
    e = e > 0.f ? e : 0.2f * e;
    ev[ne++] = e;
    lmax = fmaxf(lmax, e);
  }
#pragma unroll
  for (int off = 16; off; off >>= 1) lmax = fmaxf(lmax, __shfl_xor(lmax, off, 64));
  float lsum = 0.f;
  ne = 0;
  for (int j = l; j < cnt; j += 32) {
    float p = __expf(ev[ne++] - lmax);
    pw[h][j] = p;
    lsum += p;
  }
  for (int j = cnt + l; j < cntP; j += 32) pw[h][j] = 0.f;
#pragma unroll
  for (int off = 16; off; off >>= 1) lsum += __shfl_xor(lsum, off, 64);
  const float inv = 1.f / lsum;
  __syncthreads();

  // phase 2: gather-FMA (4 independent chains, 8 loads in flight)
  float o0 = 0.f, o1 = 0.f, o2 = 0.f, o3 = 0.f;
  const u16* wp = WHb + (t << 2);
  for (int j0 = 0; j0 < cntP; j0 += 8) {
    ushort4 buf[8];
#pragma unroll
    for (int u = 0; u < 8; ++u)
      buf[u] = *(const ushort4*)(wp + ((size_t)snb[j0 + u] << 10));
#pragma unroll
    for (int u = 0; u < 8; ++u) {
      float w = pw[h][j0 + u];
      o0 += w * bf2f(buf[u].x);
      o1 += w * bf2f(buf[u].y);
      o2 += w * bf2f(buf[u].z);
      o3 += w * bf2f(buf[u].w);
    }
  }
  o0 *= inv; o1 *= inv; o2 *= inv; o3 *= inv;

  // LN + elu + residual
  float s  = o0 + o1 + o2 + o3;
  float sq = o0 * o0 + o1 * o1 + o2 * o2 + o3 * o3;
  float mean = blockSum(s) * (1.f / 1024.f);
  float var  = blockSum(sq) * (1.f / 1024.f) - mean * mean;
  float rstd = rsqrtf(fmaxf(var, 0.f) + 1e-5f);
  float4 xv = *(float4*)&X[((size_t)n << 10) + (t << 2)];
  float ov[4] = {o0, o1, o2, o3};
  float xa[4] = {xv.x, xv.y, xv.z, xv.w};
#pragma unroll
  for (int i = 0; i < 4; ++i) {
    int c = (t << 2) + i;
    float y = (ov[i] - mean) * rstd * g[c] + b[c];
    y = y > 0.f ? y : expm1f(y);
    xa[i] += y;
  }
  *(float4*)&X[((size_t)n << 10) + (t << 2)] = make_float4(xa[0], xa[1], xa[2], xa[3]);
  ushort4 o;
  o.x = f2bf(xa[0]); o.y = f2bf(xa[1]); o.z = f2bf(xa[2]); o.w = f2bf(xa[3]);
  *(ushort4*)&Xb[((size_t)n << 10) + (t << 2)] = o;
}

// ---------------- small kernels ----------------
__global__ void build_nbr(const float* __restrict__ adj, int* __restrict__ nbr,
                          int* __restrict__ ncnt, float* __restrict__ acc) {
  __shared__ int cnt;
  int n = blockIdx.x, tid = threadIdx.x;
  if (n == 0 && tid < 2) acc[tid] = 0.f;
  if (tid == 0) cnt = 0;
  __syncthreads();
  for (int c = tid; c < NNODE; c += 256) {
    if (adj[((size_t)n << 11) + c] > 0.f) {
      int p = atomicAdd(&cnt, 1);
      if (p < CAP) nbr[n * CAP + p] = c;
    }
  }
  __syncthreads();
  if (tid == 0) ncnt[n] = cnt < CAP ? cnt : CAP;
}

__global__ __launch_bounds__(256) void cvt_dual(const float* __restrict__ in,
                                                float* __restrict__ Xf,
                                                u16* __restrict__ Xb) {
  int i = blockIdx.x * 256 + threadIdx.x;
  float4 v = ((const float4*)in)[i];
  ((float4*)Xf)[i] = v;
  ushort4 o;
  o.x = f2bf(v.x); o.y = f2bf(v.y); o.z = f2bf(v.z); o.w = f2bf(v.w);
  ((ushort4*)Xb)[i] = o;
}

__global__ __launch_bounds__(256) void qd_cvt(const float* __restrict__ q,
                                              const float* __restrict__ d,
                                              u16* __restrict__ out) {
  int i = blockIdx.x * 256 + threadIdx.x;
  const int half = BQ * ED / 4;
  const float* src = (i < half) ? q : d;
  int j = (i < half) ? i : i - half;
  float4 v = ((const float4*)src)[j];
  ushort4 o;
  o.x = f2bf(v.x); o.y = f2bf(v.y); o.z = f2bf(v.z); o.w = f2bf(v.w);
  ((ushort4*)out)[i] = o;
}

// generic fp32 [R][C] -> bf16 [C][R]
__device__ __forceinline__ void cvt_tr_body(const float* ip, u16* op, int R, int C) {
  __shared__ float T[64][65];
  int r0 = blockIdx.y * 64, c0 = blockIdx.x * 64;
  int t = threadIdx.x;
#pragma unroll
  for (int p = 0; p < 4; ++p) {
    int row = p * 16 + (t >> 4), col = (t & 15) * 4;
    float4 v = *(const float4*)&ip[(size_t)(r0 + row) * C + c0 + col];
    T[row][col] = v.x; T[row][col + 1] = v.y;
    T[row][col + 2] = v.z; T[row][col + 3] = v.w;
  }
  __syncthreads();
#pragma unroll
  for (int p = 0; p < 4; ++p) {
    int c = p * 16 + (t >> 4), r = (t & 15) * 4;
    ushort4 o;
    o.x = f2bf(T[r][c]); o.y = f2bf(T[r + 1][c]);
    o.z = f2bf(T[r + 2][c]); o.w = f2bf(T[r + 3][c]);
    *(ushort4*)&op[(size_t)(c0 + c) * R + r0 + r] = o;
  }
}

__global__ __launch_bounds__(256) void cvt_transpose(
    const float* __restrict__ in, u16* __restrict__ out,
    int R, int C, long inb, long outb) {
  cvt_tr_body(in + (size_t)blockIdx.z * inb, out + (size_t)blockIdx.z * outb, R, C);
}

// five 1024x1024 weight transposes in one launch (z selects)
__global__ __launch_bounds__(256) void cvt_transpose5(
    const float* __restrict__ i0, u16* __restrict__ o0,
    const float* __restrict__ i1, u16* __restrict__ o1,
    const float* __restrict__ i2, u16* __restrict__ o2,
    const float* __restrict__ i3, u16* __restrict__ o3,
    const float* __restrict__ i4, u16* __restrict__ o4) {
  const float* in; u16* out;
  switch (blockIdx.z) {
    case 0: in = i0; out = o0; break;
    case 1: in = i1; out = o1; break;
    case 2: in = i2; out = o2; break;
    case 3: in = i3; out = o3; break;
    default: in = i4; out = o4; break;
  }
  cvt_tr_body(in, out, 1024, 1024);
}

__global__ __launch_bounds__(256) void ln_gelu(
    const float* __restrict__ IN, u16* __restrict__ OUT,
    const float* __restrict__ g0, const float* __restrict__ b0,
    const float* __restrict__ g1, const float* __restrict__ b1) {
  int row = blockIdx.x, tid = threadIdx.x;
  const float* g = (row < 1024) ? g0 : g1;
  const float* b = (row < 1024) ? b0 : b1;
  float4 v = *(const float4*)&IN[((size_t)row << 10) + (tid << 2)];
  float s = v.x + v.y + v.z + v.w;
  float sq = v.x * v.x + v.y * v.y + v.z * v.z + v.w * v.w;
  float mean = blockSum(s) * (1.f / 1024.f);
  float var = blockSum(sq) * (1.f / 1024.f) - mean * mean;
  float rstd = rsqrtf(fmaxf(var, 0.f) + 1e-5f);
  float vals[4] = {v.x, v.y, v.z, v.w};
  ushort4 o;
  u16* oa = (u16*)&o;
#pragma unroll
  for (int i = 0; i < 4; ++i) {
    int c = (tid << 2) + i;
    float y = (vals[i] - mean) * rstd * g[c] + b[c];
    y = 0.5f * y * (1.f + erff(y * 0.70710678118654752f));
    oa[i] = f2bf(y);
  }
  *(ushort4*)&OUT[((size_t)row << 10) + (tid << 2)] = o;
}

__global__ __launch_bounds__(256) void l2norm_k(const float* __restrict__ IN,
                                                u16* __restrict__ OUT) {
  int row = blockIdx.x, tid = threadIdx.x;
  float4 v = *(const float4*)&IN[((size_t)row << 10) + (tid << 2)];
  float sq = v.x * v.x + v.y * v.y + v.z * v.z + v.w * v.w;
  float s = blockSum(sq);
  float inv = 1.f / fmaxf(sqrtf(s), 1e-12f);
  ushort4 o;
  o.x = f2bf(v.x * inv); o.y = f2bf(v.y * inv);
  o.z = f2bf(v.z * inv); o.w = f2bf(v.w * inv);
  *(ushort4*)&OUT[((size_t)row << 10) + (tid << 2)] = o;
}

__global__ __launch_bounds__(256) void lse_kernel(const float* __restrict__ NEG,
                                                  float* __restrict__ acc) {
  int bq = blockIdx.x, tid = threadIdx.x;
  const float* row = NEG + ((size_t)bq << 10);
  float4 v = *(const float4*)&row[tid << 2];
  float lm = fmaxf(fmaxf(v.x, v.y), fmaxf(v.z, v.w));
  float m = blockMax(lm);
  float ls = __expf(v.x - m) + __expf(v.y - m) + __expf(v.z - m) + __expf(v.w - m);
  float ssum = blockSum(ls);
  if (tid == 0) {
    float pos = row[bq];
    float loss = m + logf(ssum + __expf(pos - m)) - pos;
    atomicAdd(acc + 1, loss);
  }
}

__global__ void final_kernel(const float* __restrict__ acc, float* __restrict__ out) {
  float lap = acc[0] / 2048.f;
  float info = acc[1] / 1024.f;
  out[0] = info + 0.1f * lap;
  out[1] = info;
  out[2] = lap;
}

// ---------------- host launcher ----------------
extern "C" void kernel_launch(void* const* d_in, const int* in_sizes, int n_in,
                              void* d_out, int out_size, void* d_ws, size_t ws_size,
                              hipStream_t stream) {
  const float* query = (const float*)d_in[0];
  const float* docs  = (const float*)d_in[1];
  const float* nodes = (const float*)d_in[2];
  const float* adj   = (const float*)d_in[3];
  const float* lapl  = (const float*)d_in[4];
  const float* qW1 = (const float*)d_in[5],  *qb1 = (const float*)d_in[6];
  const float* qg  = (const float*)d_in[7],  *qbt = (const float*)d_in[8];
  const float* qW2 = (const float*)d_in[9],  *qb2 = (const float*)d_in[10];
  const float* dW1 = (const float*)d_in[11], *db1 = (const float*)d_in[12];
  const float* dg  = (const float*)d_in[13], *dbt = (const float*)d_in[14];
  const float* dW2 = (const float*)d_in[15], *db2 = (const float*)d_in[16];
  const float* gatW = (const float*)d_in[17];
  const float* a1   = (const float*)d_in[18];
  const float* a2   = (const float*)d_in[19];
  const float* ln_g = (const float*)d_in[20];
  const float* ln_b = (const float*)d_in[21];
  const float* poW  = (const float*)d_in[22];
  const float* pob  = (const float*)d_in[23];
  float* out = (float*)d_out;

  float* ws = (float*)d_ws;
  float* X    = ws + OFF_X;
  u16*   Xb   = (u16*)(ws + OFF_XB);
  u16*   WHb  = (u16*)(ws + OFF_WHB);
  u16*   WtG  = (u16*)(ws + OFF_WTG);
  u16*   WtPO = (u16*)(ws + OFF_WTPO);
  u16*   WtQ1 = (u16*)(ws + OFF_WTQ1);
  u16*   WtD1 = (u16*)(ws + OFF_WTD1);
  u16*   WtQ2 = (u16*)(ws + OFF_WTQ2);
  u16*   WtD2 = (u16*)(ws + OFF_WTD2);
  float* G    = ws + OFF_G;
  u16*   Gt   = (u16*)(ws + OFF_GT);
  u16*   QPb  = (u16*)(ws + OFF_QPB);
  float* Hf   = ws + OFF_HF;
  u16*   Hb   = (u16*)(ws + OFF_HB);
  float* Ff   = ws + OFF_FF;
  u16*   Fb   = (u16*)(ws + OFF_FB);
  float* NEG  = ws + OFF_NEG;
  float* S1v  = ws + OFF_SV1;
  float* S2v  = ws + OFF_SV2;
  float* ACC  = ws + OFF_ACC;
  int*   NCNT = (int*)(ws + OFF_NCNT);
  int*   NBR  = (int*)(ws + OFF_NBR);

  const size_t WSL = (size_t)GH * ED;

  // ---- prep
  build_nbr<<<NNODE, 256, 0, stream>>>(adj, NBR, NCNT, ACC);
  cvt_dual<<<2048, 256, 0, stream>>>(nodes, X, Xb);
  qd_cvt<<<2048, 256, 0, stream>>>(query, docs, QPb);
  cvt_transpose<<<dim3(2, 16, 24), 256, 0, stream>>>(
      gatW, WtG, ED, HD, (long)ED * HD, (long)HD * ED);
  cvt_transpose5<<<dim3(16, 16, 5), 256, 0, stream>>>(
      poW, WtPO, qW1, WtQ1, dW1, WtD1, qW2, WtQ2, dW2, WtD2);

  // ---- layer 0 GAT gemm (+s1s2) + MLP1
  gemm_dual<<<dim3(8, 16, 2), 256, 0, stream>>>(
      Xb, WtG, WtG, nullptr, WHb, nullptr, nullptr, NNODE, NNODE, 1.f,
      a1, a2, S1v, S2v,
      QPb, WtQ1, WtD1, Hf, nullptr, qb1, db1, 2 * BQ, BQ, 1.f);
  fused_att<<<NNODE, 256, 0, stream>>>(WHb, S1v, S2v, NBR, NCNT, X, Xb, ln_g, ln_b);
  ln_gelu<<<2 * BQ, 256, 0, stream>>>(Hf, Hb, qg, qbt, dg, dbt);

  // ---- layer 1 GAT gemm (+s1s2) + MLP2
  gemm_dual<<<dim3(8, 16, 2), 256, 0, stream>>>(
      Xb, WtG + WSL, WtG + WSL, nullptr, WHb, nullptr, nullptr, NNODE, NNODE, 1.f,
      a1 + NHEAD * HD, a2 + NHEAD * HD, S1v, S2v,
      Hb, WtQ2, WtD2, Ff, nullptr, qb2, db2, 2 * BQ, BQ, 1.f);
  fused_att<<<NNODE, 256, 0, stream>>>(WHb, S1v, S2v, NBR, NCNT, X, Xb,
      ln_g + GH, ln_b + GH);
  l2norm_k<<<2 * BQ, 256, 0, stream>>>(Ff, Fb);

  // ---- layer 2 GAT gemm (+s1s2) + NEG similarity
  gemm_dual<<<dim3(8, 16, 2), 256, 0, stream>>>(
      Xb, WtG + 2 * WSL, WtG + 2 * WSL, nullptr, WHb, nullptr, nullptr, NNODE, NNODE, 1.f,
      a1 + 2 * NHEAD * HD, a2 + 2 * NHEAD * HD, S1v, S2v,
      Fb, Fb + (size_t)BQ * ED, Fb + (size_t)BQ * ED, NEG, nullptr,
      nullptr, nullptr, BQ, BQ, 20.f);
  fused_att<<<NNODE, 256, 0, stream>>>(WHb, S1v, S2v, NBR, NCNT, X, Xb,
      ln_g + 2 * GH, ln_b + 2 * GH);
  lse_kernel<<<BQ, 256, 0, stream>>>(NEG, ACC);

  // ---- graph embeds (G fp32 + Gt bf16 in one pass) + laplacian
  gemm128<<<dim3(ED / 128, NNODE / 128), 256, 0, stream>>>(
      Xb, WtPO, WtPO, G, nullptr, Gt, pob, pob, NNODE, ED, GH, NNODE, 1.f);
  lap_gemm<<<512, 256, 0, stream>>>(lapl, Gt, G, ACC);

  final_kernel<<<1, 1, 0, stream>>>(ACC, out);
}